// Round 5
// baseline (504.278 us; speedup 1.0000x reference)
//
#include <hip/hip_runtime.h>
#include <hip/hip_bf16.h>

#define SS 2048
#define DDIM 1024

typedef unsigned short u16;
typedef unsigned int u32;
typedef __attribute__((ext_vector_type(8))) short bf16x8_t;
typedef __attribute__((ext_vector_type(4))) float f32x4_t;

__device__ __forceinline__ u16 f2bf(float f) {
  __hip_bfloat16 h = __float2bfloat16(f);
  return *reinterpret_cast<u16*>(&h);
}

// async global->LDS, 16 B per lane. LDS dest = (wave-uniform) base + lane*16.
__device__ __forceinline__ void gld16(const void* g, void* lds_base) {
  __builtin_amdgcn_global_load_lds(
      (const __attribute__((address_space(1))) u32*)(uintptr_t)g,
      (__attribute__((address_space(3))) u32*)(u32)(uintptr_t)lds_base,
      16, 0, 0);
}

// ---------------------------------------------------------------------------
__global__ void zero_kernel(u32* zb) { zb[threadIdx.x] = 0u; }

// f32 -> bf16 flat convert, 8 elems/thread; blockIdx.y selects q/k/v.
__global__ __launch_bounds__(256) void convert3_kernel(
    const float* __restrict__ q, const float* __restrict__ k,
    const float* __restrict__ v, u16* __restrict__ Xq, u16* __restrict__ Xk,
    u16* __restrict__ Xv) {
  const int z = blockIdx.y;
  const float* src = (z == 0) ? q : (z == 1) ? k : v;
  u16* dst = (z == 0) ? Xq : (z == 1) ? Xk : Xv;
  int i = blockIdx.x * 256 + threadIdx.x;
  const float4* s = (const float4*)src + (size_t)i * 2;
  float4 f0 = s[0], f1 = s[1];
  u16 o[8] = {f2bf(f0.x), f2bf(f0.y), f2bf(f0.z), f2bf(f0.w),
              f2bf(f1.x), f2bf(f1.y), f2bf(f1.z), f2bf(f1.w)};
  *(uint4*)(dst + (size_t)i * 8) = *(const uint4*)o;
}

// conv3 weight w[o][i][t] f32 -> Wr[o][t*1024+i] bf16; blockIdx.y: wq/wk.
__global__ __launch_bounds__(256) void repack3_kernel(
    const float* __restrict__ wq, const float* __restrict__ wk,
    u16* __restrict__ Wqr, u16* __restrict__ Wkr) {
  const float* w = blockIdx.y ? wk : wq;
  u16* out = blockIdx.y ? Wkr : Wqr;
  int o = blockIdx.x;
  for (int j = threadIdx.x; j < 3072; j += 256) {
    int i = j / 3, t = j - i * 3;
    out[(size_t)o * 3072 + t * 1024 + i] = f2bf(w[(size_t)o * 3072 + j]);
  }
}

// square weight [o][k] f32 -> bf16; blockIdx.y: wv/wc.
__global__ __launch_bounds__(256) void repackc_kernel(
    const float* __restrict__ wv, const float* __restrict__ wc,
    u16* __restrict__ Wvr, u16* __restrict__ Wcr) {
  const float* w = blockIdx.y ? wc : wv;
  u16* out = blockIdx.y ? Wcr : Wvr;
  size_t i = (size_t)blockIdx.x * 1024 + threadIdx.x * 4;
  float4 f = *(const float4*)(w + i);
  u16 o4[4] = {f2bf(f.x), f2bf(f.y), f2bf(f.z), f2bf(f.w)};
  *(ushort4*)(out + i) = *(const ushort4*)o4;
}

// ---------------------------------------------------------------------------
// Merged Q/K/V projection GEMM, dbuf + COUNTED vmcnt (T4). grid (32, 8, 3).
// Flattened staging: each wave issues EXACTLY 5 gld16 per tile (A granules
// c<10, B granules c>=10; every call has active lanes since kb=G%5 is mixed
// within 64 consecutive slots). Loop waits vmcnt(5) -> only the PREVIOUS
// tile's loads are drained; the just-issued prefetch stays in flight across
// the barrier (round-4's __syncthreads drained it -> zero pipelining).
// ---------------------------------------------------------------------------
__global__ __launch_bounds__(256) void mfma_proj(
    const u16* __restrict__ Xq, const u16* __restrict__ Xk,
    const u16* __restrict__ Xv, const u16* __restrict__ Wq,
    const u16* __restrict__ Wk, const u16* __restrict__ Wv,
    const float* __restrict__ bq, const float* __restrict__ bk,
    const float* __restrict__ bv, u16* __restrict__ Qhb,
    u16* __restrict__ Khb, u16* __restrict__ Vtb,
    const u16* __restrict__ zbuf) {
  __shared__ __attribute__((aligned(16))) u16 As2[2][128][40];
  __shared__ __attribute__((aligned(16))) u16 Bs2[2][128][40];
  const int z = blockIdx.z;
  const u16* __restrict__ Xb = (z == 0) ? Xq : (z == 1) ? Xk : Xv;
  const u16* __restrict__ Wr = (z == 0) ? Wq : (z == 1) ? Wk : Wv;
  const float* __restrict__ bias = (z == 0) ? bq : (z == 1) ? bk : bv;
  u16* __restrict__ Cptr = (z == 0) ? Qhb : (z == 1) ? Khb : Vtb;
  const int nk = (z == 2) ? 32 : 96;  // K-steps of 32
  const bool conv = (z < 2);
  const bool vout = (z == 2);
  const float scale = (z == 0) ? 0.125f : 1.0f;
  const int Kdim = (z == 2) ? 1024 : 3072;

  const int tid = threadIdx.x;
  const int lane = tid & 63;
  const int w = tid >> 6;
  const int ln = tid & 15;
  const int quad = (tid >> 4) & 3;
  const int wrow = w >> 1, wcol = w & 1;
  const int m0 = blockIdx.x * 128, n0 = blockIdx.y * 128;

  // stage tile ks into buffer bi: 20 wave-calls flat -> exactly 5 per wave
  auto stage = [&](int ks, int bi) {
    int k0 = ks * 32;
    for (int c = w; c < 20; c += 4) {
      if (c < 10) {
        int G = c * 64 + lane;
        int x = G / 5, kb = G - x * 5;
        if (kb < 4) {
          int gm = m0 + x;
          const u16* src;
          if (conv) {
            int b = gm >> 11, s = gm & 2047;
            int t = k0 >> 10;
            int sp = s + t - 1;
            src = (sp >= 0 && sp < SS)
                      ? Xb + ((size_t)(b * SS + sp) * DDIM + (k0 & 1023) + kb * 8)
                      : zbuf;
          } else {
            src = Xb + ((size_t)gm * DDIM + k0 + kb * 8);
          }
          gld16(src, (char*)As2[bi] + c * 1024);
        }
      } else {
        int c2 = c - 10;
        int G = c2 * 64 + lane;
        int x = G / 5, kb = G - x * 5;
        if (kb < 4)
          gld16(Wr + (size_t)(n0 + x) * Kdim + k0 + kb * 8,
                (char*)Bs2[bi] + c2 * 1024);
      }
    }
  };

  f32x4_t acc[4][4];
#pragma unroll
  for (int i = 0; i < 4; ++i)
#pragma unroll
    for (int j = 0; j < 4; ++j) acc[i][j] = (f32x4_t){0.f, 0.f, 0.f, 0.f};

  stage(0, 0);  // 5 outstanding/wave; no drain here

  for (int ks = 0; ks < nk; ++ks) {
    int cur = ks & 1;
    bool more = (ks + 1 < nk);
    if (more) {
      stage(ks + 1, cur ^ 1);  // +5 -> 10 outstanding
      asm volatile("s_waitcnt vmcnt(5)" ::: "memory");  // tile-ks landed
    } else {
      asm volatile("s_waitcnt vmcnt(0)" ::: "memory");
    }
    __builtin_amdgcn_s_barrier();        // all waves' tile-ks loads visible
    __builtin_amdgcn_sched_barrier(0);   // pin ds_reads below the barrier

    const u16(*As)[40] = As2[cur];
    const u16(*Bs)[40] = Bs2[cur];
    bf16x8_t a[4], b[4];
#pragma unroll
    for (int mt = 0; mt < 4; ++mt)
      a[mt] = *(const bf16x8_t*)&As[wrow * 64 + mt * 16 + ln][quad * 8];
#pragma unroll
    for (int nt = 0; nt < 4; ++nt)
      b[nt] = *(const bf16x8_t*)&Bs[wcol * 64 + nt * 16 + ln][quad * 8];
#pragma unroll
    for (int mt = 0; mt < 4; ++mt)
#pragma unroll
      for (int nt = 0; nt < 4; ++nt)
        acc[mt][nt] = __builtin_amdgcn_mfma_f32_16x16x32_bf16(
            a[mt], b[nt], acc[mt][nt], 0, 0, 0);

    asm volatile("s_waitcnt lgkmcnt(0)" ::: "memory");  // my reads in regs
    __builtin_amdgcn_s_barrier();        // everyone done reading buf cur
    __builtin_amdgcn_sched_barrier(0);   // pin next stage below
  }

#pragma unroll
  for (int mt = 0; mt < 4; ++mt) {
#pragma unroll
    for (int nt = 0; nt < 4; ++nt) {
      int gn = n0 + wcol * 64 + nt * 16 + ln;
      float bi = bias[gn];
#pragma unroll
      for (int r = 0; r < 4; ++r) {
        int gm = m0 + wrow * 64 + mt * 16 + quad * 4 + r;
        float val = (acc[mt][nt][r] + bi) * scale;
        int b = gm >> 11, s = gm & 2047;
        int hh = gn & 15, dd = gn >> 4;  // channel = dd*16 + hh (head FAST)
        if (!vout)
          Cptr[((size_t)(b * 16 + hh) * SS + s) * 64 + dd] = f2bf(val);
        else
          Cptr[((size_t)(b * 16 + hh) * 64 + dd) * SS + s] = f2bf(val);
      }
    }
  }
}

// ---------------------------------------------------------------------------
// Final linear GEMM, dbuf + counted vmcnt. 32x128 tile, grid (128, 8).
// Flat staging c<13: A granules c<3, B granules c>=3.
// Per-wave issue counts: w0=4, w1..w3=3.
// ---------------------------------------------------------------------------
__global__ __launch_bounds__(256) void mfma_gemm_lin(
    const u16* __restrict__ Xb, const u16* __restrict__ Wr,
    const float* __restrict__ bias, float* __restrict__ Cptr) {
  __shared__ __attribute__((aligned(16))) u16 As2[2][32][40];
  __shared__ __attribute__((aligned(16))) u16 Bs2[2][128][40];
  const int tid = threadIdx.x;
  const int lane = tid & 63;
  const int w = tid >> 6;
  const int ln = tid & 15;
  const int quad = (tid >> 4) & 3;
  const int wrow = w >> 1, wcol = w & 1;
  const int m0 = blockIdx.x * 32, n0 = blockIdx.y * 128;

  auto stage = [&](int ks, int bi) {
    int k0 = ks * 32;
    for (int c = w; c < 13; c += 4) {
      if (c < 3) {
        int G = c * 64 + lane;
        int x = G / 5, kb = G - x * 5;
        if (kb < 4 && x < 32)
          gld16(Xb + ((size_t)(m0 + x) * DDIM + k0 + kb * 8),
                (char*)As2[bi] + c * 1024);
      } else {
        int c2 = c - 3;
        int G = c2 * 64 + lane;
        int x = G / 5, kb = G - x * 5;
        if (kb < 4)
          gld16(Wr + (size_t)(n0 + x) * 1024 + k0 + kb * 8,
                (char*)Bs2[bi] + c2 * 1024);
      }
    }
  };

  f32x4_t acc[4];
#pragma unroll
  for (int j = 0; j < 4; ++j) acc[j] = (f32x4_t){0.f, 0.f, 0.f, 0.f};

  stage(0, 0);

  for (int ks = 0; ks < 32; ++ks) {
    int cur = ks & 1;
    bool more = (ks + 1 < 32);
    if (more) {
      stage(ks + 1, cur ^ 1);
      if (w == 0) asm volatile("s_waitcnt vmcnt(4)" ::: "memory");
      else        asm volatile("s_waitcnt vmcnt(3)" ::: "memory");
    } else {
      asm volatile("s_waitcnt vmcnt(0)" ::: "memory");
    }
    __builtin_amdgcn_s_barrier();
    __builtin_amdgcn_sched_barrier(0);

    const u16(*As)[40] = As2[cur];
    const u16(*Bs)[40] = Bs2[cur];
    bf16x8_t a = *(const bf16x8_t*)&As[wrow * 16 + ln][quad * 8];
    bf16x8_t b[4];
#pragma unroll
    for (int nt = 0; nt < 4; ++nt)
      b[nt] = *(const bf16x8_t*)&Bs[wcol * 64 + nt * 16 + ln][quad * 8];
#pragma unroll
    for (int nt = 0; nt < 4; ++nt)
      acc[nt] = __builtin_amdgcn_mfma_f32_16x16x32_bf16(a, b[nt], acc[nt], 0, 0, 0);

    asm volatile("s_waitcnt lgkmcnt(0)" ::: "memory");
    __builtin_amdgcn_s_barrier();
    __builtin_amdgcn_sched_barrier(0);
  }

#pragma unroll
  for (int nt = 0; nt < 4; ++nt) {
    int gn = n0 + wcol * 64 + nt * 16 + ln;
    float bi = bias[gn];
#pragma unroll
    for (int r = 0; r < 4; ++r) {
      int gm = m0 + wrow * 16 + quad * 4 + r;
      Cptr[(size_t)gm * DDIM + gn] = acc[nt][r] + bi;
    }
  }
}

// ---------------------------------------------------------------------------
// MFMA flash attention, dbuf + counted vmcnt. Flat staging c<18: K granules
// c<9, V granules c>=9. Per-wave issue counts: w0,w1=5; w2,w3=4.
// Prefetch flies under QK^T + softmax + PV (long compute phase).
// ---------------------------------------------------------------------------
__global__ __launch_bounds__(256) void mfma_attn(
    const u16* __restrict__ Qhb, const u16* __restrict__ Khb,
    const u16* __restrict__ Vtb, u16* __restrict__ Aob,
    const u16* __restrict__ zbuf) {
  __shared__ __attribute__((aligned(16))) u16 Ks2[2][64][72];
  __shared__ __attribute__((aligned(16))) u16 Vt2[2][64][72];
  __shared__ __attribute__((aligned(16))) u16 Ps[4][16][72];
  const int tid = threadIdx.x;
  const int lane = tid & 63;
  const int w = tid >> 6;
  const int ln = tid & 15;
  const int quad = (tid >> 4) & 3;
  const int bh = blockIdx.y;
  const int b = bh >> 4, hh = bh & 15;
  const int s0 = blockIdx.x * 64;

  auto stage = [&](int kt, int bi) {
    for (int c = w; c < 18; c += 4) {
      if (c < 9) {
        int G = c * 64 + lane;
        int x = G / 9, db = G - x * 9;
        if (db < 8)
          gld16(Khb + ((size_t)bh * SS + kt * 64 + x) * 64 + db * 8,
                (char*)Ks2[bi] + c * 1024);
      } else {
        int c2 = c - 9;
        int G = c2 * 64 + lane;
        int x = G / 9, db = G - x * 9;
        if (db < 8)
          gld16(Vtb + ((size_t)bh * 64 + x) * SS + kt * 64 + db * 8,
                (char*)Vt2[bi] + c2 * 1024);
      }
    }
  };

  const u16* qp = Qhb + ((size_t)bh * SS + s0 + w * 16 + ln) * 64 + quad * 8;
  bf16x8_t qf0 = *(const bf16x8_t*)qp;
  bf16x8_t qf1 = *(const bf16x8_t*)(qp + 32);

  float mrow[4], lsum[4];
  f32x4_t oacc[4];
#pragma unroll
  for (int r = 0; r < 4; ++r) { mrow[r] = -3e38f; lsum[r] = 0.f; }
#pragma unroll
  for (int dt = 0; dt < 4; ++dt) oacc[dt] = (f32x4_t){0.f, 0.f, 0.f, 0.f};

  stage(0, 0);

  for (int kt = 0; kt < 32; ++kt) {
    int cur = kt & 1;
    bool more = (kt + 1 < 32);
    if (more) {
      stage(kt + 1, cur ^ 1);
      if (w < 2) asm volatile("s_waitcnt vmcnt(5)" ::: "memory");
      else       asm volatile("s_waitcnt vmcnt(4)" ::: "memory");
    } else {
      asm volatile("s_waitcnt vmcnt(0)" ::: "memory");
    }
    __builtin_amdgcn_s_barrier();
    __builtin_amdgcn_sched_barrier(0);

    const u16(*Ks)[72] = Ks2[cur];
    const u16(*Vt)[72] = Vt2[cur];

    f32x4_t sc[4];
#pragma unroll
    for (int nt = 0; nt < 4; ++nt) sc[nt] = (f32x4_t){0.f, 0.f, 0.f, 0.f};
#pragma unroll
    for (int nt = 0; nt < 4; ++nt) {
      bf16x8_t k0f = *(const bf16x8_t*)&Ks[nt * 16 + ln][quad * 8];
      sc[nt] = __builtin_amdgcn_mfma_f32_16x16x32_bf16(qf0, k0f, sc[nt], 0, 0, 0);
      bf16x8_t k1f = *(const bf16x8_t*)&Ks[nt * 16 + ln][32 + quad * 8];
      sc[nt] = __builtin_amdgcn_mfma_f32_16x16x32_bf16(qf1, k1f, sc[nt], 0, 0, 0);
    }

    // row max reduce (quad group); wave-uniform deferred rescale
    float mxv[4];
    bool need = false;
#pragma unroll
    for (int r = 0; r < 4; ++r) {
      float mx = fmaxf(fmaxf(sc[0][r], sc[1][r]), fmaxf(sc[2][r], sc[3][r]));
      mx = fmaxf(mx, __shfl_xor(mx, 1, 64));
      mx = fmaxf(mx, __shfl_xor(mx, 2, 64));
      mx = fmaxf(mx, __shfl_xor(mx, 4, 64));
      mx = fmaxf(mx, __shfl_xor(mx, 8, 64));
      mxv[r] = mx;
      need = need || (mx > mrow[r]);
    }
    if (__any(need)) {
#pragma unroll
      for (int r = 0; r < 4; ++r) {
        float mn = fmaxf(mrow[r], mxv[r]);
        float al = __expf(mrow[r] - mn);
        mrow[r] = mn;
        lsum[r] *= al;
#pragma unroll
        for (int dt = 0; dt < 4; ++dt) oacc[dt][r] *= al;
      }
    }
#pragma unroll
    for (int r = 0; r < 4; ++r) {
      float p0 = __expf(sc[0][r] - mrow[r]), p1 = __expf(sc[1][r] - mrow[r]);
      float p2 = __expf(sc[2][r] - mrow[r]), p3 = __expf(sc[3][r] - mrow[r]);
      lsum[r] += p0 + p1 + p2 + p3;
      Ps[w][quad * 4 + r][ln] = f2bf(p0);
      Ps[w][quad * 4 + r][16 + ln] = f2bf(p1);
      Ps[w][quad * 4 + r][32 + ln] = f2bf(p2);
      Ps[w][quad * 4 + r][48 + ln] = f2bf(p3);
    }

    // PV (P read back in A-operand layout; same-wave LDS program order)
    bf16x8_t pa0 = *(const bf16x8_t*)&Ps[w][ln][quad * 8];
    bf16x8_t pa1 = *(const bf16x8_t*)&Ps[w][ln][32 + quad * 8];
#pragma unroll
    for (int dt = 0; dt < 4; ++dt) {
      bf16x8_t v0f = *(const bf16x8_t*)&Vt[dt * 16 + ln][quad * 8];
      oacc[dt] = __builtin_amdgcn_mfma_f32_16x16x32_bf16(pa0, v0f, oacc[dt], 0, 0, 0);
      bf16x8_t v1f = *(const bf16x8_t*)&Vt[dt * 16 + ln][32 + quad * 8];
      oacc[dt] = __builtin_amdgcn_mfma_f32_16x16x32_bf16(pa1, v1f, oacc[dt], 0, 0, 0);
    }

    asm volatile("s_waitcnt lgkmcnt(0)" ::: "memory");
    __builtin_amdgcn_s_barrier();
    __builtin_amdgcn_sched_barrier(0);
  }

  // epilogue: reduce lane-partial sums once, normalize, store
  float inv[4];
#pragma unroll
  for (int r = 0; r < 4; ++r) {
    float t = lsum[r];
    t += __shfl_xor(t, 1, 64);
    t += __shfl_xor(t, 2, 64);
    t += __shfl_xor(t, 4, 64);
    t += __shfl_xor(t, 8, 64);
    inv[r] = 1.f / t;
  }
#pragma unroll
  for (int dt = 0; dt < 4; ++dt)
#pragma unroll
    for (int r = 0; r < 4; ++r) {
      int gm = b * SS + s0 + w * 16 + quad * 4 + r;
      Aob[(size_t)gm * DDIM + hh * 64 + dt * 16 + ln] = f2bf(oacc[dt][r] * inv[r]);
    }
}

// ---------------------------------------------------------------------------
// Launch
// ---------------------------------------------------------------------------
extern "C" void kernel_launch(void* const* d_in, const int* in_sizes, int n_in,
                              void* d_out, int out_size, void* d_ws, size_t ws_size,
                              hipStream_t stream) {
  const float* q    = (const float*)d_in[0];
  const float* k    = (const float*)d_in[1];
  const float* v    = (const float*)d_in[2];
  const float* wq_w = (const float*)d_in[3];
  const float* wq_b = (const float*)d_in[4];
  const float* wk_w = (const float*)d_in[5];
  const float* wk_b = (const float*)d_in[6];
  const float* wv_w = (const float*)d_in[7];
  const float* wv_b = (const float*)d_in[8];
  const float* wc_w = (const float*)d_in[9];
  const float* wc_b = (const float*)d_in[10];

  char* ws = (char*)d_ws;
  size_t off = 0;
  u16* zbuf = (u16*)(ws + off); off += 256;
  const size_t SZ_ACT = (size_t)2 * SS * DDIM * 2;  // 8 MB bf16
  u16* Xq  = (u16*)(ws + off); off += SZ_ACT;
  u16* Xk  = (u16*)(ws + off); off += SZ_ACT;
  u16* Xv  = (u16*)(ws + off); off += SZ_ACT;
  u16* Wqr = (u16*)(ws + off); off += (size_t)1024 * 3072 * 2;
  u16* Wkr = (u16*)(ws + off); off += (size_t)1024 * 3072 * 2;
  u16* Wvr = (u16*)(ws + off); off += (size_t)1024 * 1024 * 2;
  u16* Wcr = (u16*)(ws + off); off += (size_t)1024 * 1024 * 2;
  u16* Qhb = (u16*)(ws + off); off += SZ_ACT;
  u16* Khb = (u16*)(ws + off); off += SZ_ACT;
  u16* Vtb = (u16*)(ws + off); off += SZ_ACT;
  u16* Aob = (u16*)(ws + off); off += SZ_ACT;
  if (ws_size < off) return;

  zero_kernel<<<1, 64, 0, stream>>>((u32*)zbuf);
  convert3_kernel<<<dim3(2048, 3), 256, 0, stream>>>(q, k, v, Xq, Xk, Xv);
  repack3_kernel<<<dim3(1024, 2), 256, 0, stream>>>(wq_w, wk_w, Wqr, Wkr);
  repackc_kernel<<<dim3(1024, 2), 256, 0, stream>>>(wv_w, wc_w, Wvr, Wcr);

  // merged Q/K/V projections, dbuf + counted vmcnt
  mfma_proj<<<dim3(32, 8, 3), 256, 0, stream>>>(
      Xq, Xk, Xv, Wqr, Wkr, Wvr, wq_b, wk_b, wv_b, Qhb, Khb, Vtb, zbuf);

  mfma_attn<<<dim3(32, 32), 256, 0, stream>>>(Qhb, Khb, Vtb, Aob, zbuf);

  mfma_gemm_lin<<<dim3(128, 8), 256, 0, stream>>>(Aob, Wcr, wc_b, (float*)d_out);
}

// Round 6
// 394.855 us; speedup vs baseline: 1.2771x; 1.2771x over previous
//
#include <hip/hip_runtime.h>
#include <hip/hip_bf16.h>

#define SS 2048
#define DDIM 1024

typedef unsigned short u16;
typedef unsigned int u32;
typedef __attribute__((ext_vector_type(8))) short bf16x8_t;
typedef __attribute__((ext_vector_type(4))) float f32x4_t;

__device__ __forceinline__ u16 f2bf(float f) {
  __hip_bfloat16 h = __float2bfloat16(f);
  return *reinterpret_cast<u16*>(&h);
}

// async global->LDS, 16 B per lane. LDS dest = (wave-uniform) base + lane*16.
__device__ __forceinline__ void gld16(const void* g, void* lds_base) {
  __builtin_amdgcn_global_load_lds(
      (const __attribute__((address_space(1))) u32*)(uintptr_t)g,
      (__attribute__((address_space(3))) u32*)(u32)(uintptr_t)lds_base,
      16, 0, 0);
}

// ---------------------------------------------------------------------------
__global__ void zero_kernel(u32* zb) { zb[threadIdx.x] = 0u; }

// f32 -> bf16 flat convert, 8 elems/thread; blockIdx.y selects q/k/v.
__global__ __launch_bounds__(256) void convert3_kernel(
    const float* __restrict__ q, const float* __restrict__ k,
    const float* __restrict__ v, u16* __restrict__ Xq, u16* __restrict__ Xk,
    u16* __restrict__ Xv) {
  const int z = blockIdx.y;
  const float* src = (z == 0) ? q : (z == 1) ? k : v;
  u16* dst = (z == 0) ? Xq : (z == 1) ? Xk : Xv;
  int i = blockIdx.x * 256 + threadIdx.x;
  const float4* s = (const float4*)src + (size_t)i * 2;
  float4 f0 = s[0], f1 = s[1];
  u16 o[8] = {f2bf(f0.x), f2bf(f0.y), f2bf(f0.z), f2bf(f0.w),
              f2bf(f1.x), f2bf(f1.y), f2bf(f1.z), f2bf(f1.w)};
  *(uint4*)(dst + (size_t)i * 8) = *(const uint4*)o;
}

// conv3 weight w[o][i][t] f32 -> Wr[o][t*1024+i] bf16; blockIdx.y: wq/wk.
__global__ __launch_bounds__(256) void repack3_kernel(
    const float* __restrict__ wq, const float* __restrict__ wk,
    u16* __restrict__ Wqr, u16* __restrict__ Wkr) {
  const float* w = blockIdx.y ? wk : wq;
  u16* out = blockIdx.y ? Wkr : Wqr;
  int o = blockIdx.x;
  for (int j = threadIdx.x; j < 3072; j += 256) {
    int i = j / 3, t = j - i * 3;
    out[(size_t)o * 3072 + t * 1024 + i] = f2bf(w[(size_t)o * 3072 + j]);
  }
}

// square weight [o][k] f32 -> bf16; blockIdx.y: wv/wc.
__global__ __launch_bounds__(256) void repackc_kernel(
    const float* __restrict__ wv, const float* __restrict__ wc,
    u16* __restrict__ Wvr, u16* __restrict__ Wcr) {
  const float* w = blockIdx.y ? wc : wv;
  u16* out = blockIdx.y ? Wcr : Wvr;
  size_t i = (size_t)blockIdx.x * 1024 + threadIdx.x * 4;
  float4 f = *(const float4*)(w + i);
  u16 o4[4] = {f2bf(f.x), f2bf(f.y), f2bf(f.z), f2bf(f.w)};
  *(ushort4*)(out + i) = *(const ushort4*)o4;
}

// ---------------------------------------------------------------------------
// Merged Q/K/V projection GEMM. grid (32, 8, 3). 128x128 tile, BK=32.
// T3 one-barrier loop: stage(next)->compute(cur)->vmcnt(0)+barrier; the
// prefetch flies over the whole ds_read+MFMA phase (r2/r4 drained it
// immediately -> zero overlap; r5's counted pins serialized VALU).
// Staging addresses HOISTED: 5 per-slot pointers/wave in VGPRs, one add per
// slot per step. Conv pointer is linear across all 96 steps (stepping +64 B
// walks cols then wraps to the shifted row); OOB rows freeze on zbuf, with
// a twice-per-kernel uniform fixup at phase boundaries (t=0->1: unfreeze
// s==0 rows; t=1->2: freeze s==2047 rows).
// ---------------------------------------------------------------------------
__global__ __launch_bounds__(256) void mfma_proj(
    const u16* __restrict__ Xq, const u16* __restrict__ Xk,
    const u16* __restrict__ Xv, const u16* __restrict__ Wq,
    const u16* __restrict__ Wk, const u16* __restrict__ Wv,
    const float* __restrict__ bq, const float* __restrict__ bk,
    const float* __restrict__ bv, u16* __restrict__ Qhb,
    u16* __restrict__ Khb, u16* __restrict__ Vtb,
    const u16* __restrict__ zbuf) {
  __shared__ __attribute__((aligned(16))) u16 As2[2][128][40];
  __shared__ __attribute__((aligned(16))) u16 Bs2[2][128][40];
  const int z = blockIdx.z;
  const u16* __restrict__ Xb = (z == 0) ? Xq : (z == 1) ? Xk : Xv;
  const u16* __restrict__ Wr = (z == 0) ? Wq : (z == 1) ? Wk : Wv;
  const float* __restrict__ bias = (z == 0) ? bq : (z == 1) ? bk : bv;
  u16* __restrict__ Cptr = (z == 0) ? Qhb : (z == 1) ? Khb : Vtb;
  const int nk = (z == 2) ? 32 : 96;
  const bool conv = (z < 2);
  const bool vout = (z == 2);
  const float scale = (z == 0) ? 0.125f : 1.0f;
  const int Kdim = (z == 2) ? 1024 : 3072;

  const int tid = threadIdx.x;
  const int lane = tid & 63;
  const int w = tid >> 6;
  const int ln = tid & 15;
  const int quad = (tid >> 4) & 3;
  const int wrow = w >> 1, wcol = w & 1;
  const int m0 = blockIdx.x * 128, n0 = blockIdx.y * 128;

  // ---- hoisted per-slot staging state (slot i: c = w + 4i) ----
  const char* p[5];
  int dinc[5];
  u32 ldso[5];
  bool act[5], isA[5], loA[5], hiA[5];
  const char* pbaseA[5];

#pragma unroll
  for (int i = 0; i < 5; ++i) {
    int c = w + 4 * i;
    isA[i] = (c < 10);
    if (c < 10) {
      int G = c * 64 + lane;
      int x = G / 5, kb = G - x * 5;
      int gm = m0 + x;
      int b = gm >> 11, s = gm & 2047;
      act[i] = (kb < 4);
      ldso[i] = c * 1024;
      const char* pb = (const char*)(Xb + (size_t)(b * SS + s) * DDIM + kb * 8);
      pbaseA[i] = pb;
      loA[i] = (s == 0);
      hiA[i] = (s == 2047);
      if (conv) {
        p[i] = loA[i] ? (const char*)zbuf : (pb - 2048);  // t=0: row s-1
        dinc[i] = loA[i] ? 0 : 64;
      } else {
        p[i] = pb;
        dinc[i] = 64;
      }
    } else {
      int c2 = c - 10;
      int G = c2 * 64 + lane;
      int x = G / 5, kb = G - x * 5;
      act[i] = (kb < 4);
      ldso[i] = c2 * 1024;
      p[i] = (const char*)(Wr + (size_t)(n0 + x) * Kdim + kb * 8);
      dinc[i] = 64;
      pbaseA[i] = nullptr;
      loA[i] = hiA[i] = false;
    }
  }

  auto stage = [&](int bi) {
#pragma unroll
    for (int i = 0; i < 5; ++i) {
      char* dst = (isA[i] ? (char*)As2[bi] : (char*)Bs2[bi]) + ldso[i];
      if (act[i]) gld16(p[i], dst);
      p[i] += dinc[i];
    }
  };

  f32x4_t acc[4][4];
#pragma unroll
  for (int i = 0; i < 4; ++i)
#pragma unroll
    for (int j = 0; j < 4; ++j) acc[i][j] = (f32x4_t){0.f, 0.f, 0.f, 0.f};

  stage(0);
  asm volatile("s_waitcnt vmcnt(0)" ::: "memory");
  __builtin_amdgcn_s_barrier();

#pragma unroll 2
  for (int ks = 0; ks < nk; ++ks) {
    const int cur = ks & 1;
    const int j = ks + 1;
    if (j < nk) {
      if (conv && (j & 31) == 0) {  // phase boundary for next staged tile
#pragma unroll
        for (int i = 0; i < 5; ++i) {
          if (isA[i]) {
            if (j == 32) {  // entering t=1: unfreeze s==0 rows
              if (loA[i]) { p[i] = pbaseA[i]; dinc[i] = 64; }
            } else {        // entering t=2: freeze s==2047 rows
              if (hiA[i]) { p[i] = (const char*)zbuf; dinc[i] = 0; }
            }
          }
        }
      }
      stage(cur ^ 1);  // flies over the compute phase below
    }

    const u16(*As)[40] = As2[cur];
    const u16(*Bs)[40] = Bs2[cur];
    bf16x8_t a[4], b[4];
#pragma unroll
    for (int mt = 0; mt < 4; ++mt)
      a[mt] = *(const bf16x8_t*)&As[wrow * 64 + mt * 16 + ln][quad * 8];
#pragma unroll
    for (int nt = 0; nt < 4; ++nt)
      b[nt] = *(const bf16x8_t*)&Bs[wcol * 64 + nt * 16 + ln][quad * 8];
    __builtin_amdgcn_s_setprio(1);
#pragma unroll
    for (int mt = 0; mt < 4; ++mt)
#pragma unroll
      for (int nt = 0; nt < 4; ++nt)
        acc[mt][nt] = __builtin_amdgcn_mfma_f32_16x16x32_bf16(
            a[mt], b[nt], acc[mt][nt], 0, 0, 0);
    __builtin_amdgcn_s_setprio(0);

    asm volatile("s_waitcnt vmcnt(0) lgkmcnt(0)" ::: "memory");
    __builtin_amdgcn_s_barrier();
  }

#pragma unroll
  for (int mt = 0; mt < 4; ++mt) {
#pragma unroll
    for (int nt = 0; nt < 4; ++nt) {
      int gn = n0 + wcol * 64 + nt * 16 + ln;
      float bi = bias[gn];
#pragma unroll
      for (int r = 0; r < 4; ++r) {
        int gm = m0 + wrow * 64 + mt * 16 + quad * 4 + r;
        float val = (acc[mt][nt][r] + bi) * scale;
        int b = gm >> 11, s = gm & 2047;
        int hh = gn & 15, dd = gn >> 4;  // channel = dd*16 + hh (head FAST)
        if (!vout)
          Cptr[((size_t)(b * 16 + hh) * SS + s) * 64 + dd] = f2bf(val);
        else
          Cptr[((size_t)(b * 16 + hh) * 64 + dd) * SS + s] = f2bf(val);
      }
    }
  }
}

// ---------------------------------------------------------------------------
// Final linear GEMM. 32x128 tile, grid (128, 8). Same T3 one-barrier loop +
// hoisted slot pointers (w0: 4 slots, w1..3: 3 slots; vmcnt(0) so per-wave
// counts don't matter).
// ---------------------------------------------------------------------------
__global__ __launch_bounds__(256) void mfma_gemm_lin(
    const u16* __restrict__ Xb, const u16* __restrict__ Wr,
    const float* __restrict__ bias, float* __restrict__ Cptr) {
  __shared__ __attribute__((aligned(16))) u16 As2[2][32][40];
  __shared__ __attribute__((aligned(16))) u16 Bs2[2][128][40];
  const int tid = threadIdx.x;
  const int lane = tid & 63;
  const int w = tid >> 6;
  const int ln = tid & 15;
  const int quad = (tid >> 4) & 3;
  const int wrow = w >> 1, wcol = w & 1;
  const int m0 = blockIdx.x * 32, n0 = blockIdx.y * 128;

  const char* p[4];
  u32 ldso[4];
  bool ok[4], act[4], isA[4];
#pragma unroll
  for (int i = 0; i < 4; ++i) {
    int c = w + 4 * i;
    ok[i] = (c < 13);
    if (c < 3) {
      int G = c * 64 + lane;
      int x = G / 5, kb = G - x * 5;
      isA[i] = true;
      act[i] = (kb < 4) && (x < 32);
      ldso[i] = c * 1024;
      p[i] = (const char*)(Xb + (size_t)(m0 + x) * DDIM + kb * 8);
    } else if (c < 13) {
      int c2 = c - 3;
      int G = c2 * 64 + lane;
      int x = G / 5, kb = G - x * 5;
      isA[i] = false;
      act[i] = (kb < 4);
      ldso[i] = c2 * 1024;
      p[i] = (const char*)(Wr + (size_t)(n0 + x) * 1024 + kb * 8);
    } else {
      isA[i] = false; act[i] = false; ldso[i] = 0; p[i] = nullptr;
    }
  }

  auto stage = [&](int bi) {
#pragma unroll
    for (int i = 0; i < 4; ++i) {
      if (ok[i]) {
        char* dst = (isA[i] ? (char*)As2[bi] : (char*)Bs2[bi]) + ldso[i];
        if (act[i]) gld16(p[i], dst);
        p[i] += 64;
      }
    }
  };

  f32x4_t acc[4];
#pragma unroll
  for (int j = 0; j < 4; ++j) acc[j] = (f32x4_t){0.f, 0.f, 0.f, 0.f};

  stage(0);
  asm volatile("s_waitcnt vmcnt(0)" ::: "memory");
  __builtin_amdgcn_s_barrier();

#pragma unroll 2
  for (int ks = 0; ks < 32; ++ks) {
    const int cur = ks & 1;
    if (ks + 1 < 32) stage(cur ^ 1);

    const u16(*As)[40] = As2[cur];
    const u16(*Bs)[40] = Bs2[cur];
    bf16x8_t a = *(const bf16x8_t*)&As[wrow * 16 + ln][quad * 8];
    bf16x8_t b[4];
#pragma unroll
    for (int nt = 0; nt < 4; ++nt)
      b[nt] = *(const bf16x8_t*)&Bs[wcol * 64 + nt * 16 + ln][quad * 8];
    __builtin_amdgcn_s_setprio(1);
#pragma unroll
    for (int nt = 0; nt < 4; ++nt)
      acc[nt] = __builtin_amdgcn_mfma_f32_16x16x32_bf16(a, b[nt], acc[nt], 0, 0, 0);
    __builtin_amdgcn_s_setprio(0);

    asm volatile("s_waitcnt vmcnt(0) lgkmcnt(0)" ::: "memory");
    __builtin_amdgcn_s_barrier();
  }

#pragma unroll
  for (int nt = 0; nt < 4; ++nt) {
    int gn = n0 + wcol * 64 + nt * 16 + ln;
    float bi = bias[gn];
#pragma unroll
    for (int r = 0; r < 4; ++r) {
      int gm = m0 + wrow * 16 + quad * 4 + r;
      Cptr[(size_t)gm * DDIM + gn] = acc[nt][r] + bi;
    }
  }
}

// ---------------------------------------------------------------------------
// MFMA flash attention. T3 one-barrier loop: K/V prefetch for kt+1 flies
// over QK^T + softmax + Ps + PV of tile kt (~full hide). Hoisted slot
// pointers (K: +8192 B/tile, V: +128 B/tile). Softmax unchanged (lane-
// partial lsum + deferred rescale, verified r2-r5).
// ---------------------------------------------------------------------------
__global__ __launch_bounds__(256) void mfma_attn(
    const u16* __restrict__ Qhb, const u16* __restrict__ Khb,
    const u16* __restrict__ Vtb, u16* __restrict__ Aob,
    const u16* __restrict__ zbuf) {
  __shared__ __attribute__((aligned(16))) u16 Ks2[2][64][72];
  __shared__ __attribute__((aligned(16))) u16 Vt2[2][64][72];
  __shared__ __attribute__((aligned(16))) u16 Ps[4][16][72];
  const int tid = threadIdx.x;
  const int lane = tid & 63;
  const int w = tid >> 6;
  const int ln = tid & 15;
  const int quad = (tid >> 4) & 3;
  const int bh = blockIdx.y;
  const int b = bh >> 4, hh = bh & 15;
  const int s0 = blockIdx.x * 64;

  const char* p[5];
  int dinc[5];
  u32 ldso[5];
  bool ok[5], act[5], isK[5];
#pragma unroll
  for (int i = 0; i < 5; ++i) {
    int c = w + 4 * i;
    ok[i] = (c < 18);
    if (c < 9) {
      int G = c * 64 + lane;
      int x = G / 9, db = G - x * 9;
      isK[i] = true;
      act[i] = (db < 8);
      ldso[i] = c * 1024;
      p[i] = (const char*)(Khb + ((size_t)bh * SS + x) * 64 + db * 8);
      dinc[i] = 8192;  // +64 rows of 64 elems per K-tile
    } else if (c < 18) {
      int c2 = c - 9;
      int G = c2 * 64 + lane;
      int x = G / 9, db = G - x * 9;
      isK[i] = false;
      act[i] = (db < 8);
      ldso[i] = c2 * 1024;
      p[i] = (const char*)(Vtb + ((size_t)bh * 64 + x) * SS + db * 8);
      dinc[i] = 128;  // +64 elems per K-tile
    } else {
      isK[i] = false; ok[i] = false; act[i] = false; ldso[i] = 0;
      p[i] = nullptr; dinc[i] = 0;
    }
  }

  auto stage = [&](int bi) {
#pragma unroll
    for (int i = 0; i < 5; ++i) {
      if (ok[i]) {
        char* dst = (isK[i] ? (char*)Ks2[bi] : (char*)Vt2[bi]) + ldso[i];
        if (act[i]) gld16(p[i], dst);
        p[i] += dinc[i];
      }
    }
  };

  const u16* qp = Qhb + ((size_t)bh * SS + s0 + w * 16 + ln) * 64 + quad * 8;
  bf16x8_t qf0 = *(const bf16x8_t*)qp;
  bf16x8_t qf1 = *(const bf16x8_t*)(qp + 32);

  float mrow[4], lsum[4];
  f32x4_t oacc[4];
#pragma unroll
  for (int r = 0; r < 4; ++r) { mrow[r] = -3e38f; lsum[r] = 0.f; }
#pragma unroll
  for (int dt = 0; dt < 4; ++dt) oacc[dt] = (f32x4_t){0.f, 0.f, 0.f, 0.f};

  stage(0);
  asm volatile("s_waitcnt vmcnt(0)" ::: "memory");
  __builtin_amdgcn_s_barrier();

#pragma unroll 2
  for (int kt = 0; kt < 32; ++kt) {
    const int cur = kt & 1;
    if (kt + 1 < 32) stage(cur ^ 1);  // flies over the whole tile compute

    const u16(*Ks)[72] = Ks2[cur];
    const u16(*Vt)[72] = Vt2[cur];

    f32x4_t sc[4];
#pragma unroll
    for (int nt = 0; nt < 4; ++nt) sc[nt] = (f32x4_t){0.f, 0.f, 0.f, 0.f};
    __builtin_amdgcn_s_setprio(1);
#pragma unroll
    for (int nt = 0; nt < 4; ++nt) {
      bf16x8_t k0f = *(const bf16x8_t*)&Ks[nt * 16 + ln][quad * 8];
      sc[nt] = __builtin_amdgcn_mfma_f32_16x16x32_bf16(qf0, k0f, sc[nt], 0, 0, 0);
      bf16x8_t k1f = *(const bf16x8_t*)&Ks[nt * 16 + ln][32 + quad * 8];
      sc[nt] = __builtin_amdgcn_mfma_f32_16x16x32_bf16(qf1, k1f, sc[nt], 0, 0, 0);
    }
    __builtin_amdgcn_s_setprio(0);

    // row max reduce (quad group); wave-uniform deferred rescale
    float mxv[4];
    bool need = false;
#pragma unroll
    for (int r = 0; r < 4; ++r) {
      float mx = fmaxf(fmaxf(sc[0][r], sc[1][r]), fmaxf(sc[2][r], sc[3][r]));
      mx = fmaxf(mx, __shfl_xor(mx, 1, 64));
      mx = fmaxf(mx, __shfl_xor(mx, 2, 64));
      mx = fmaxf(mx, __shfl_xor(mx, 4, 64));
      mx = fmaxf(mx, __shfl_xor(mx, 8, 64));
      mxv[r] = mx;
      need = need || (mx > mrow[r]);
    }
    if (__any(need)) {
#pragma unroll
      for (int r = 0; r < 4; ++r) {
        float mn = fmaxf(mrow[r], mxv[r]);
        float al = __expf(mrow[r] - mn);
        mrow[r] = mn;
        lsum[r] *= al;
#pragma unroll
        for (int dt = 0; dt < 4; ++dt) oacc[dt][r] *= al;
      }
    }
#pragma unroll
    for (int r = 0; r < 4; ++r) {
      float p0 = __expf(sc[0][r] - mrow[r]), p1 = __expf(sc[1][r] - mrow[r]);
      float p2 = __expf(sc[2][r] - mrow[r]), p3 = __expf(sc[3][r] - mrow[r]);
      lsum[r] += p0 + p1 + p2 + p3;
      Ps[w][quad * 4 + r][ln] = f2bf(p0);
      Ps[w][quad * 4 + r][16 + ln] = f2bf(p1);
      Ps[w][quad * 4 + r][32 + ln] = f2bf(p2);
      Ps[w][quad * 4 + r][48 + ln] = f2bf(p3);
    }

    // PV (P read back in A-operand layout; same-wave LDS program order)
    bf16x8_t pa0 = *(const bf16x8_t*)&Ps[w][ln][quad * 8];
    bf16x8_t pa1 = *(const bf16x8_t*)&Ps[w][ln][32 + quad * 8];
    __builtin_amdgcn_s_setprio(1);
#pragma unroll
    for (int dt = 0; dt < 4; ++dt) {
      bf16x8_t v0f = *(const bf16x8_t*)&Vt[dt * 16 + ln][quad * 8];
      oacc[dt] = __builtin_amdgcn_mfma_f32_16x16x32_bf16(pa0, v0f, oacc[dt], 0, 0, 0);
      bf16x8_t v1f = *(const bf16x8_t*)&Vt[dt * 16 + ln][32 + quad * 8];
      oacc[dt] = __builtin_amdgcn_mfma_f32_16x16x32_bf16(pa1, v1f, oacc[dt], 0, 0, 0);
    }
    __builtin_amdgcn_s_setprio(0);

    asm volatile("s_waitcnt vmcnt(0) lgkmcnt(0)" ::: "memory");
    __builtin_amdgcn_s_barrier();
  }

  // epilogue: reduce lane-partial sums once, normalize, store
  float inv[4];
#pragma unroll
  for (int r = 0; r < 4; ++r) {
    float t = lsum[r];
    t += __shfl_xor(t, 1, 64);
    t += __shfl_xor(t, 2, 64);
    t += __shfl_xor(t, 4, 64);
    t += __shfl_xor(t, 8, 64);
    inv[r] = 1.f / t;
  }
#pragma unroll
  for (int dt = 0; dt < 4; ++dt)
#pragma unroll
    for (int r = 0; r < 4; ++r) {
      int gm = b * SS + s0 + w * 16 + quad * 4 + r;
      Aob[(size_t)gm * DDIM + hh * 64 + dt * 16 + ln] = f2bf(oacc[dt][r] * inv[r]);
    }
}

// ---------------------------------------------------------------------------
// Launch
// ---------------------------------------------------------------------------
extern "C" void kernel_launch(void* const* d_in, const int* in_sizes, int n_in,
                              void* d_out, int out_size, void* d_ws, size_t ws_size,
                              hipStream_t stream) {
  const float* q    = (const float*)d_in[0];
  const float* k    = (const float*)d_in[1];
  const float* v    = (const float*)d_in[2];
  const float* wq_w = (const float*)d_in[3];
  const float* wq_b = (const float*)d_in[4];
  const float* wk_w = (const float*)d_in[5];
  const float* wk_b = (const float*)d_in[6];
  const float* wv_w = (const float*)d_in[7];
  const float* wv_b = (const float*)d_in[8];
  const float* wc_w = (const float*)d_in[9];
  const float* wc_b = (const float*)d_in[10];

  char* ws = (char*)d_ws;
  size_t off = 0;
  u16* zbuf = (u16*)(ws + off); off += 256;
  const size_t SZ_ACT = (size_t)2 * SS * DDIM * 2;  // 8 MB bf16
  u16* Xq  = (u16*)(ws + off); off += SZ_ACT;
  u16* Xk  = (u16*)(ws + off); off += SZ_ACT;
  u16* Xv  = (u16*)(ws + off); off += SZ_ACT;
  u16* Wqr = (u16*)(ws + off); off += (size_t)1024 * 3072 * 2;
  u16* Wkr = (u16*)(ws + off); off += (size_t)1024 * 3072 * 2;
  u16* Wvr = (u16*)(ws + off); off += (size_t)1024 * 1024 * 2;
  u16* Wcr = (u16*)(ws + off); off += (size_t)1024 * 1024 * 2;
  u16* Qhb = (u16*)(ws + off); off += SZ_ACT;
  u16* Khb = (u16*)(ws + off); off += SZ_ACT;
  u16* Vtb = (u16*)(ws + off); off += SZ_ACT;
  u16* Aob = (u16*)(ws + off); off += SZ_ACT;
  if (ws_size < off) return;

  zero_kernel<<<1, 64, 0, stream>>>((u32*)zbuf);
  convert3_kernel<<<dim3(2048, 3), 256, 0, stream>>>(q, k, v, Xq, Xk, Xv);
  repack3_kernel<<<dim3(1024, 2), 256, 0, stream>>>(wq_w, wk_w, Wqr, Wkr);
  repackc_kernel<<<dim3(1024, 2), 256, 0, stream>>>(wv_w, wc_w, Wvr, Wcr);

  // merged Q/K/V projections: T3 one-barrier pipeline + hoisted addressing
  mfma_proj<<<dim3(32, 8, 3), 256, 0, stream>>>(
      Xq, Xk, Xv, Wqr, Wkr, Wvr, wq_b, wk_b, wv_b, Qhb, Khb, Vtb, zbuf);

  mfma_attn<<<dim3(32, 32), 256, 0, stream>>>(Qhb, Khb, Vtb, Aob, zbuf);

  mfma_gemm_lin<<<dim3(128, 8), 256, 0, stream>>>(Aob, Wcr, wc_b, (float*)d_out);
}

// Round 7
// 393.068 us; speedup vs baseline: 1.2829x; 1.0045x over previous
//
#include <hip/hip_runtime.h>
#include <hip/hip_bf16.h>

#define SS 2048
#define DDIM 1024

typedef unsigned short u16;
typedef unsigned int u32;
typedef __attribute__((ext_vector_type(8))) short bf16x8_t;
typedef __attribute__((ext_vector_type(4))) float f32x4_t;

__device__ __forceinline__ u16 f2bf(float f) {
  __hip_bfloat16 h = __float2bfloat16(f);
  return *reinterpret_cast<u16*>(&h);
}

// async global->LDS, 16 B per lane. LDS dest = (wave-uniform) base + lane*16.
__device__ __forceinline__ void gld16(const void* g, void* lds_base) {
  __builtin_amdgcn_global_load_lds(
      (const __attribute__((address_space(1))) u32*)(uintptr_t)g,
      (__attribute__((address_space(3))) u32*)(u32)(uintptr_t)lds_base,
      16, 0, 0);
}

// ---------------------------------------------------------------------------
__global__ void zero_kernel(u32* zb) { zb[threadIdx.x] = 0u; }

// f32 -> bf16 flat convert, 8 elems/thread; blockIdx.y selects q/k/v.
__global__ __launch_bounds__(256) void convert3_kernel(
    const float* __restrict__ q, const float* __restrict__ k,
    const float* __restrict__ v, u16* __restrict__ Xq, u16* __restrict__ Xk,
    u16* __restrict__ Xv) {
  const int z = blockIdx.y;
  const float* src = (z == 0) ? q : (z == 1) ? k : v;
  u16* dst = (z == 0) ? Xq : (z == 1) ? Xk : Xv;
  int i = blockIdx.x * 256 + threadIdx.x;
  const float4* s = (const float4*)src + (size_t)i * 2;
  float4 f0 = s[0], f1 = s[1];
  u16 o[8] = {f2bf(f0.x), f2bf(f0.y), f2bf(f0.z), f2bf(f0.w),
              f2bf(f1.x), f2bf(f1.y), f2bf(f1.z), f2bf(f1.w)};
  *(uint4*)(dst + (size_t)i * 8) = *(const uint4*)o;
}

// conv3 weight w[o][i][t] f32 -> Wr[o][t*1024+i] bf16; blockIdx.y: wq/wk.
__global__ __launch_bounds__(256) void repack3_kernel(
    const float* __restrict__ wq, const float* __restrict__ wk,
    u16* __restrict__ Wqr, u16* __restrict__ Wkr) {
  const float* w = blockIdx.y ? wk : wq;
  u16* out = blockIdx.y ? Wkr : Wqr;
  int o = blockIdx.x;
  for (int j = threadIdx.x; j < 3072; j += 256) {
    int i = j / 3, t = j - i * 3;
    out[(size_t)o * 3072 + t * 1024 + i] = f2bf(w[(size_t)o * 3072 + j]);
  }
}

// square weight [o][k] f32 -> bf16; blockIdx.y: wv/wc.
__global__ __launch_bounds__(256) void repackc_kernel(
    const float* __restrict__ wv, const float* __restrict__ wc,
    u16* __restrict__ Wvr, u16* __restrict__ Wcr) {
  const float* w = blockIdx.y ? wc : wv;
  u16* out = blockIdx.y ? Wcr : Wvr;
  size_t i = (size_t)blockIdx.x * 1024 + threadIdx.x * 4;
  float4 f = *(const float4*)(w + i);
  u16 o4[4] = {f2bf(f.x), f2bf(f.y), f2bf(f.z), f2bf(f.w)};
  *(ushort4*)(out + i) = *(const ushort4*)o4;
}

// ---------------------------------------------------------------------------
// Merged Q/K/V projection GEMM. grid (32, 8, 3). 128x128 tile, BK=32.
// 2-deep counted-vmcnt pipeline (T4): prologue stages tiles 0,1; each iter
// waits vmcnt(5) (= its own tile's 5 loads, issued 2 iterations earlier),
// reads frags, barriers, then stages tile ks+2 into the just-freed buffer.
// Loads fly over ~2 full iterations. Waitcnt+barrier fused in one asm so
// no memory op can slip between. Staging addresses hoisted (r6): 5 per-slot
// pointers/wave, +64 B/step; conv OOB rows freeze on zbuf with uniform
// fixups when STAGED tile crosses t-phase (j==32 unfreeze s==0, j==64
// freeze s==2047).
// ---------------------------------------------------------------------------
__global__ __launch_bounds__(256) void mfma_proj(
    const u16* __restrict__ Xq, const u16* __restrict__ Xk,
    const u16* __restrict__ Xv, const u16* __restrict__ Wq,
    const u16* __restrict__ Wk, const u16* __restrict__ Wv,
    const float* __restrict__ bq, const float* __restrict__ bk,
    const float* __restrict__ bv, u16* __restrict__ Qhb,
    u16* __restrict__ Khb, u16* __restrict__ Vtb,
    const u16* __restrict__ zbuf) {
  __shared__ __attribute__((aligned(16))) u16 As2[2][128][40];
  __shared__ __attribute__((aligned(16))) u16 Bs2[2][128][40];
  const int z = blockIdx.z;
  const u16* __restrict__ Xb = (z == 0) ? Xq : (z == 1) ? Xk : Xv;
  const u16* __restrict__ Wr = (z == 0) ? Wq : (z == 1) ? Wk : Wv;
  const float* __restrict__ bias = (z == 0) ? bq : (z == 1) ? bk : bv;
  u16* __restrict__ Cptr = (z == 0) ? Qhb : (z == 1) ? Khb : Vtb;
  const int nk = (z == 2) ? 32 : 96;
  const bool conv = (z < 2);
  const bool vout = (z == 2);
  const float scale = (z == 0) ? 0.125f : 1.0f;
  const int Kdim = (z == 2) ? 1024 : 3072;

  const int tid = threadIdx.x;
  const int lane = tid & 63;
  const int w = tid >> 6;
  const int ln = tid & 15;
  const int quad = (tid >> 4) & 3;
  const int wrow = w >> 1, wcol = w & 1;
  const int m0 = blockIdx.x * 128, n0 = blockIdx.y * 128;

  // ---- hoisted per-slot staging state (slot i: c = w + 4i) ----
  const char* p[5];
  int dinc[5];
  u32 ldso[5];
  bool act[5], isA[5], loA[5], hiA[5];
  const char* pbaseA[5];

#pragma unroll
  for (int i = 0; i < 5; ++i) {
    int c = w + 4 * i;
    isA[i] = (c < 10);
    if (c < 10) {
      int G = c * 64 + lane;
      int x = G / 5, kb = G - x * 5;
      int gm = m0 + x;
      int b = gm >> 11, s = gm & 2047;
      act[i] = (kb < 4);
      ldso[i] = c * 1024;
      const char* pb = (const char*)(Xb + (size_t)(b * SS + s) * DDIM + kb * 8);
      pbaseA[i] = pb;
      loA[i] = (s == 0);
      hiA[i] = (s == 2047);
      if (conv) {
        p[i] = loA[i] ? (const char*)zbuf : (pb - 2048);  // t=0: row s-1
        dinc[i] = loA[i] ? 0 : 64;
      } else {
        p[i] = pb;
        dinc[i] = 64;
      }
    } else {
      int c2 = c - 10;
      int G = c2 * 64 + lane;
      int x = G / 5, kb = G - x * 5;
      act[i] = (kb < 4);
      ldso[i] = c2 * 1024;
      p[i] = (const char*)(Wr + (size_t)(n0 + x) * Kdim + kb * 8);
      dinc[i] = 64;
      pbaseA[i] = nullptr;
      loA[i] = hiA[i] = false;
    }
  }

  // each call issues EXACTLY 5 gld16 per wave (vmcnt accounting relies on it)
  auto stage = [&](int bi) {
#pragma unroll
    for (int i = 0; i < 5; ++i) {
      char* dst = (isA[i] ? (char*)As2[bi] : (char*)Bs2[bi]) + ldso[i];
      if (act[i]) gld16(p[i], dst);
      p[i] += dinc[i];
    }
  };

  f32x4_t acc[4][4];
#pragma unroll
  for (int i = 0; i < 4; ++i)
#pragma unroll
    for (int j = 0; j < 4; ++j) acc[i][j] = (f32x4_t){0.f, 0.f, 0.f, 0.f};

  stage(0);  // tile 0 -> buf 0
  stage(1);  // tile 1 -> buf 1 (10 outstanding/wave)

#pragma unroll 2
  for (int ks = 0; ks < nk; ++ks) {
    const int cur = ks & 1;
    // wait for tile-ks loads (oldest 5); keep tile ks+1 in flight
    if (ks + 1 < nk)
      asm volatile("s_waitcnt vmcnt(5)\ns_barrier" ::: "memory");
    else
      asm volatile("s_waitcnt vmcnt(0)\ns_barrier" ::: "memory");

    const u16(*As)[40] = As2[cur];
    const u16(*Bs)[40] = Bs2[cur];
    bf16x8_t a[4], b[4];
#pragma unroll
    for (int mt = 0; mt < 4; ++mt)
      a[mt] = *(const bf16x8_t*)&As[wrow * 64 + mt * 16 + ln][quad * 8];
#pragma unroll
    for (int nt = 0; nt < 4; ++nt)
      b[nt] = *(const bf16x8_t*)&Bs[wcol * 64 + nt * 16 + ln][quad * 8];
    asm volatile("s_waitcnt lgkmcnt(0)\ns_barrier" ::: "memory");

    const int j = ks + 2;
    if (j < nk) {
      if (conv && (j & 31) == 0) {  // staged tile crosses a t-phase boundary
#pragma unroll
        for (int i = 0; i < 5; ++i) {
          if (isA[i]) {
            if (j == 32) {  // entering t=1: unfreeze s==0 rows
              if (loA[i]) { p[i] = pbaseA[i]; dinc[i] = 64; }
            } else {        // entering t=2: freeze s==2047 rows
              if (hiA[i]) { p[i] = (const char*)zbuf; dinc[i] = 0; }
            }
          }
        }
      }
      stage(cur);  // tile ks+2 -> just-freed buffer; flies 2 iterations
    }

    __builtin_amdgcn_s_setprio(1);
#pragma unroll
    for (int mt = 0; mt < 4; ++mt)
#pragma unroll
      for (int nt = 0; nt < 4; ++nt)
        acc[mt][nt] = __builtin_amdgcn_mfma_f32_16x16x32_bf16(
            a[mt], b[nt], acc[mt][nt], 0, 0, 0);
    __builtin_amdgcn_s_setprio(0);
  }

#pragma unroll
  for (int mt = 0; mt < 4; ++mt) {
#pragma unroll
    for (int nt = 0; nt < 4; ++nt) {
      int gn = n0 + wcol * 64 + nt * 16 + ln;
      float bi = bias[gn];
#pragma unroll
      for (int r = 0; r < 4; ++r) {
        int gm = m0 + wrow * 64 + mt * 16 + quad * 4 + r;
        float val = (acc[mt][nt][r] + bi) * scale;
        int b = gm >> 11, s = gm & 2047;
        int hh = gn & 15, dd = gn >> 4;  // channel = dd*16 + hh (head FAST)
        if (!vout)
          Cptr[((size_t)(b * 16 + hh) * SS + s) * 64 + dd] = f2bf(val);
        else
          Cptr[((size_t)(b * 16 + hh) * 64 + dd) * SS + s] = f2bf(val);
      }
    }
  }
}

// ---------------------------------------------------------------------------
// Final linear GEMM. 32x128 tile, grid (128, 8). Same 2-deep counted
// pipeline; per-wave issue counts: w0=4, w1..3=3.
// ---------------------------------------------------------------------------
__global__ __launch_bounds__(256) void mfma_gemm_lin(
    const u16* __restrict__ Xb, const u16* __restrict__ Wr,
    const float* __restrict__ bias, float* __restrict__ Cptr) {
  __shared__ __attribute__((aligned(16))) u16 As2[2][32][40];
  __shared__ __attribute__((aligned(16))) u16 Bs2[2][128][40];
  const int tid = threadIdx.x;
  const int lane = tid & 63;
  const int w = tid >> 6;
  const int ln = tid & 15;
  const int quad = (tid >> 4) & 3;
  const int wrow = w >> 1, wcol = w & 1;
  const int m0 = blockIdx.x * 32, n0 = blockIdx.y * 128;

  const char* p[4];
  u32 ldso[4];
  bool ok[4], act[4], isA[4];
#pragma unroll
  for (int i = 0; i < 4; ++i) {
    int c = w + 4 * i;
    ok[i] = (c < 13);
    if (c < 3) {
      int G = c * 64 + lane;
      int x = G / 5, kb = G - x * 5;
      isA[i] = true;
      act[i] = (kb < 4) && (x < 32);
      ldso[i] = c * 1024;
      p[i] = (const char*)(Xb + (size_t)(m0 + x) * DDIM + kb * 8);
    } else if (c < 13) {
      int c2 = c - 3;
      int G = c2 * 64 + lane;
      int x = G / 5, kb = G - x * 5;
      isA[i] = false;
      act[i] = (kb < 4);
      ldso[i] = c2 * 1024;
      p[i] = (const char*)(Wr + (size_t)(n0 + x) * 1024 + kb * 8);
    } else {
      isA[i] = false; act[i] = false; ldso[i] = 0; p[i] = nullptr;
    }
  }

  auto stage = [&](int bi) {
#pragma unroll
    for (int i = 0; i < 4; ++i) {
      if (ok[i]) {
        char* dst = (isA[i] ? (char*)As2[bi] : (char*)Bs2[bi]) + ldso[i];
        if (act[i]) gld16(p[i], dst);
        p[i] += 64;
      }
    }
  };

  f32x4_t acc[4];
#pragma unroll
  for (int j = 0; j < 4; ++j) acc[j] = (f32x4_t){0.f, 0.f, 0.f, 0.f};

  stage(0);
  stage(1);

#pragma unroll 2
  for (int ks = 0; ks < 32; ++ks) {
    const int cur = ks & 1;
    if (ks + 1 < 32) {
      if (w == 0) asm volatile("s_waitcnt vmcnt(4)\ns_barrier" ::: "memory");
      else        asm volatile("s_waitcnt vmcnt(3)\ns_barrier" ::: "memory");
    } else {
      asm volatile("s_waitcnt vmcnt(0)\ns_barrier" ::: "memory");
    }

    const u16(*As)[40] = As2[cur];
    const u16(*Bs)[40] = Bs2[cur];
    bf16x8_t a = *(const bf16x8_t*)&As[wrow * 16 + ln][quad * 8];
    bf16x8_t b[4];
#pragma unroll
    for (int nt = 0; nt < 4; ++nt)
      b[nt] = *(const bf16x8_t*)&Bs[wcol * 64 + nt * 16 + ln][quad * 8];
    asm volatile("s_waitcnt lgkmcnt(0)\ns_barrier" ::: "memory");

    if (ks + 2 < 32) stage(cur);

    __builtin_amdgcn_s_setprio(1);
#pragma unroll
    for (int nt = 0; nt < 4; ++nt)
      acc[nt] = __builtin_amdgcn_mfma_f32_16x16x32_bf16(a, b[nt], acc[nt], 0, 0, 0);
    __builtin_amdgcn_s_setprio(0);
  }

#pragma unroll
  for (int nt = 0; nt < 4; ++nt) {
    int gn = n0 + wcol * 64 + nt * 16 + ln;
    float bi = bias[gn];
#pragma unroll
    for (int r = 0; r < 4; ++r) {
      int gm = m0 + wrow * 16 + quad * 4 + r;
      Cptr[(size_t)gm * DDIM + gn] = acc[nt][r] + bi;
    }
  }
}

// ---------------------------------------------------------------------------
// MFMA flash attention. 2-deep counted pipeline: tile kt+2 staged at the
// BOTTOM of iter kt (after the read-done barrier), consumed at the top of
// iter kt+2 -> flies over the whole of iter kt+1 (QK^T+softmax+PV).
// Per-wave issue counts: w0,w1=5; w2,w3=4.
// ---------------------------------------------------------------------------
__global__ __launch_bounds__(256) void mfma_attn(
    const u16* __restrict__ Qhb, const u16* __restrict__ Khb,
    const u16* __restrict__ Vtb, u16* __restrict__ Aob,
    const u16* __restrict__ zbuf) {
  __shared__ __attribute__((aligned(16))) u16 Ks2[2][64][72];
  __shared__ __attribute__((aligned(16))) u16 Vt2[2][64][72];
  __shared__ __attribute__((aligned(16))) u16 Ps[4][16][72];
  const int tid = threadIdx.x;
  const int lane = tid & 63;
  const int w = tid >> 6;
  const int ln = tid & 15;
  const int quad = (tid >> 4) & 3;
  const int bh = blockIdx.y;
  const int b = bh >> 4, hh = bh & 15;
  const int s0 = blockIdx.x * 64;

  const char* p[5];
  int dinc[5];
  u32 ldso[5];
  bool ok[5], act[5], isK[5];
#pragma unroll
  for (int i = 0; i < 5; ++i) {
    int c = w + 4 * i;
    ok[i] = (c < 18);
    if (c < 9) {
      int G = c * 64 + lane;
      int x = G / 9, db = G - x * 9;
      isK[i] = true;
      act[i] = (db < 8);
      ldso[i] = c * 1024;
      p[i] = (const char*)(Khb + ((size_t)bh * SS + x) * 64 + db * 8);
      dinc[i] = 8192;  // +64 rows of 64 elems per K-tile
    } else if (c < 18) {
      int c2 = c - 9;
      int G = c2 * 64 + lane;
      int x = G / 9, db = G - x * 9;
      isK[i] = false;
      act[i] = (db < 8);
      ldso[i] = c2 * 1024;
      p[i] = (const char*)(Vtb + ((size_t)bh * 64 + x) * SS + db * 8);
      dinc[i] = 128;  // +64 elems per K-tile
    } else {
      isK[i] = false; ok[i] = false; act[i] = false; ldso[i] = 0;
      p[i] = nullptr; dinc[i] = 0;
    }
  }

  auto stage = [&](int bi) {
#pragma unroll
    for (int i = 0; i < 5; ++i) {
      if (ok[i]) {
        char* dst = (isK[i] ? (char*)Ks2[bi] : (char*)Vt2[bi]) + ldso[i];
        if (act[i]) gld16(p[i], dst);
        p[i] += dinc[i];
      }
    }
  };

  const u16* qp = Qhb + ((size_t)bh * SS + s0 + w * 16 + ln) * 64 + quad * 8;
  bf16x8_t qf0 = *(const bf16x8_t*)qp;
  bf16x8_t qf1 = *(const bf16x8_t*)(qp + 32);

  float mrow[4], lsum[4];
  f32x4_t oacc[4];
#pragma unroll
  for (int r = 0; r < 4; ++r) { mrow[r] = -3e38f; lsum[r] = 0.f; }
#pragma unroll
  for (int dt = 0; dt < 4; ++dt) oacc[dt] = (f32x4_t){0.f, 0.f, 0.f, 0.f};

  stage(0);  // tile 0 -> buf 0
  stage(1);  // tile 1 -> buf 1

#pragma unroll 2
  for (int kt = 0; kt < 32; ++kt) {
    const int cur = kt & 1;
    if (kt + 1 < 32) {
      if (w < 2) asm volatile("s_waitcnt vmcnt(5)\ns_barrier" ::: "memory");
      else       asm volatile("s_waitcnt vmcnt(4)\ns_barrier" ::: "memory");
    } else {
      asm volatile("s_waitcnt vmcnt(0)\ns_barrier" ::: "memory");
    }

    const u16(*Ks)[72] = Ks2[cur];
    const u16(*Vt)[72] = Vt2[cur];

    f32x4_t sc[4];
#pragma unroll
    for (int nt = 0; nt < 4; ++nt) sc[nt] = (f32x4_t){0.f, 0.f, 0.f, 0.f};
    __builtin_amdgcn_s_setprio(1);
#pragma unroll
    for (int nt = 0; nt < 4; ++nt) {
      bf16x8_t k0f = *(const bf16x8_t*)&Ks[nt * 16 + ln][quad * 8];
      sc[nt] = __builtin_amdgcn_mfma_f32_16x16x32_bf16(qf0, k0f, sc[nt], 0, 0, 0);
      bf16x8_t k1f = *(const bf16x8_t*)&Ks[nt * 16 + ln][32 + quad * 8];
      sc[nt] = __builtin_amdgcn_mfma_f32_16x16x32_bf16(qf1, k1f, sc[nt], 0, 0, 0);
    }
    __builtin_amdgcn_s_setprio(0);

    // row max reduce (quad group); wave-uniform deferred rescale
    float mxv[4];
    bool need = false;
#pragma unroll
    for (int r = 0; r < 4; ++r) {
      float mx = fmaxf(fmaxf(sc[0][r], sc[1][r]), fmaxf(sc[2][r], sc[3][r]));
      mx = fmaxf(mx, __shfl_xor(mx, 1, 64));
      mx = fmaxf(mx, __shfl_xor(mx, 2, 64));
      mx = fmaxf(mx, __shfl_xor(mx, 4, 64));
      mx = fmaxf(mx, __shfl_xor(mx, 8, 64));
      mxv[r] = mx;
      need = need || (mx > mrow[r]);
    }
    if (__any(need)) {
#pragma unroll
      for (int r = 0; r < 4; ++r) {
        float mn = fmaxf(mrow[r], mxv[r]);
        float al = __expf(mrow[r] - mn);
        mrow[r] = mn;
        lsum[r] *= al;
#pragma unroll
        for (int dt = 0; dt < 4; ++dt) oacc[dt][r] *= al;
      }
    }
#pragma unroll
    for (int r = 0; r < 4; ++r) {
      float p0 = __expf(sc[0][r] - mrow[r]), p1 = __expf(sc[1][r] - mrow[r]);
      float p2 = __expf(sc[2][r] - mrow[r]), p3 = __expf(sc[3][r] - mrow[r]);
      lsum[r] += p0 + p1 + p2 + p3;
      Ps[w][quad * 4 + r][ln] = f2bf(p0);
      Ps[w][quad * 4 + r][16 + ln] = f2bf(p1);
      Ps[w][quad * 4 + r][32 + ln] = f2bf(p2);
      Ps[w][quad * 4 + r][48 + ln] = f2bf(p3);
    }

    // PV (P read back in A-operand layout; same-wave LDS program order)
    bf16x8_t pa0 = *(const bf16x8_t*)&Ps[w][ln][quad * 8];
    bf16x8_t pa1 = *(const bf16x8_t*)&Ps[w][ln][32 + quad * 8];
    __builtin_amdgcn_s_setprio(1);
#pragma unroll
    for (int dt = 0; dt < 4; ++dt) {
      bf16x8_t v0f = *(const bf16x8_t*)&Vt[dt * 16 + ln][quad * 8];
      oacc[dt] = __builtin_amdgcn_mfma_f32_16x16x32_bf16(pa0, v0f, oacc[dt], 0, 0, 0);
      bf16x8_t v1f = *(const bf16x8_t*)&Vt[dt * 16 + ln][32 + quad * 8];
      oacc[dt] = __builtin_amdgcn_mfma_f32_16x16x32_bf16(pa1, v1f, oacc[dt], 0, 0, 0);
    }
    __builtin_amdgcn_s_setprio(0);

    asm volatile("s_waitcnt lgkmcnt(0)\ns_barrier" ::: "memory");
    if (kt + 2 < 32) stage(cur);  // tile kt+2; flies over all of iter kt+1
  }

  // epilogue: reduce lane-partial sums once, normalize, store
  float inv[4];
#pragma unroll
  for (int r = 0; r < 4; ++r) {
    float t = lsum[r];
    t += __shfl_xor(t, 1, 64);
    t += __shfl_xor(t, 2, 64);
    t += __shfl_xor(t, 4, 64);
    t += __shfl_xor(t, 8, 64);
    inv[r] = 1.f / t;
  }
#pragma unroll
  for (int dt = 0; dt < 4; ++dt)
#pragma unroll
    for (int r = 0; r < 4; ++r) {
      int gm = b * SS + s0 + w * 16 + quad * 4 + r;
      Aob[(size_t)gm * DDIM + hh * 64 + dt * 16 + ln] = f2bf(oacc[dt][r] * inv[r]);
    }
}

// ---------------------------------------------------------------------------
// Launch
// ---------------------------------------------------------------------------
extern "C" void kernel_launch(void* const* d_in, const int* in_sizes, int n_in,
                              void* d_out, int out_size, void* d_ws, size_t ws_size,
                              hipStream_t stream) {
  const float* q    = (const float*)d_in[0];
  const float* k    = (const float*)d_in[1];
  const float* v    = (const float*)d_in[2];
  const float* wq_w = (const float*)d_in[3];
  const float* wq_b = (const float*)d_in[4];
  const float* wk_w = (const float*)d_in[5];
  const float* wk_b = (const float*)d_in[6];
  const float* wv_w = (const float*)d_in[7];
  const float* wv_b = (const float*)d_in[8];
  const float* wc_w = (const float*)d_in[9];
  const float* wc_b = (const float*)d_in[10];

  char* ws = (char*)d_ws;
  size_t off = 0;
  u16* zbuf = (u16*)(ws + off); off += 256;
  const size_t SZ_ACT = (size_t)2 * SS * DDIM * 2;  // 8 MB bf16
  u16* Xq  = (u16*)(ws + off); off += SZ_ACT;
  u16* Xk  = (u16*)(ws + off); off += SZ_ACT;
  u16* Xv  = (u16*)(ws + off); off += SZ_ACT;
  u16* Wqr = (u16*)(ws + off); off += (size_t)1024 * 3072 * 2;
  u16* Wkr = (u16*)(ws + off); off += (size_t)1024 * 3072 * 2;
  u16* Wvr = (u16*)(ws + off); off += (size_t)1024 * 1024 * 2;
  u16* Wcr = (u16*)(ws + off); off += (size_t)1024 * 1024 * 2;
  u16* Qhb = (u16*)(ws + off); off += SZ_ACT;
  u16* Khb = (u16*)(ws + off); off += SZ_ACT;
  u16* Vtb = (u16*)(ws + off); off += SZ_ACT;
  u16* Aob = (u16*)(ws + off); off += SZ_ACT;
  if (ws_size < off) return;

  zero_kernel<<<1, 64, 0, stream>>>((u32*)zbuf);
  convert3_kernel<<<dim3(2048, 3), 256, 0, stream>>>(q, k, v, Xq, Xk, Xv);
  repack3_kernel<<<dim3(1024, 2), 256, 0, stream>>>(wq_w, wk_w, Wqr, Wkr);
  repackc_kernel<<<dim3(1024, 2), 256, 0, stream>>>(wv_w, wc_w, Wvr, Wcr);

  // merged Q/K/V projections: 2-deep counted-vmcnt pipeline
  mfma_proj<<<dim3(32, 8, 3), 256, 0, stream>>>(
      Xq, Xk, Xv, Wqr, Wkr, Wvr, wq_b, wk_b, wv_b, Qhb, Khb, Vtb, zbuf);

  mfma_attn<<<dim3(32, 32), 256, 0, stream>>>(Qhb, Khb, Vtb, Aob, zbuf);

  mfma_gemm_lin<<<dim3(128, 8), 256, 0, stream>>>(Aob, Wcr, wc_b, (float*)d_out);
}

// Round 8
// 366.123 us; speedup vs baseline: 1.3773x; 1.0736x over previous
//
#include <hip/hip_runtime.h>
#include <hip/hip_bf16.h>

#define SS 2048
#define DDIM 1024

typedef unsigned short u16;
typedef unsigned int u32;
typedef __attribute__((ext_vector_type(8))) short bf16x8_t;
typedef __attribute__((ext_vector_type(4))) float f32x4_t;

__device__ __forceinline__ u16 f2bf(float f) {
  __hip_bfloat16 h = __float2bfloat16(f);
  return *reinterpret_cast<u16*>(&h);
}

// async global->LDS, 16 B per lane. LDS dest = (wave-uniform) base + lane*16.
__device__ __forceinline__ void gld16(const void* g, void* lds_base) {
  __builtin_amdgcn_global_load_lds(
      (const __attribute__((address_space(1))) u32*)(uintptr_t)g,
      (__attribute__((address_space(3))) u32*)(u32)(uintptr_t)lds_base,
      16, 0, 0);
}

// ---------------------------------------------------------------------------
// Fused prep: zbuf zero + f32->bf16 converts + weight repacks. Grid 10240:
//   [0,6144):    convert q/k/v (2048 blocks each)
//   [6144,8192): repack3 wq (1024) / wk (1024)
//   [8192,10240): repackc wv (1024) / wc (1024)
// ---------------------------------------------------------------------------
__global__ __launch_bounds__(256) void prep_kernel(
    const float* __restrict__ q, const float* __restrict__ k,
    const float* __restrict__ v, const float* __restrict__ wq_w,
    const float* __restrict__ wk_w, const float* __restrict__ wv_w,
    const float* __restrict__ wc_w, u16* __restrict__ Xq,
    u16* __restrict__ Xk, u16* __restrict__ Xv, u16* __restrict__ Wqr,
    u16* __restrict__ Wkr, u16* __restrict__ Wvr, u16* __restrict__ Wcr,
    u32* __restrict__ zbuf) {
  const int bid = blockIdx.x;
  const int tid = threadIdx.x;
  if (bid == 0 && tid < 64) zbuf[tid] = 0u;

  if (bid < 6144) {
    const int z = bid >> 11;            // 0..2
    const int bx = bid & 2047;
    const float* src = (z == 0) ? q : (z == 1) ? k : v;
    u16* dst = (z == 0) ? Xq : (z == 1) ? Xk : Xv;
    int i = bx * 256 + tid;
    const float4* s = (const float4*)src + (size_t)i * 2;
    float4 f0 = s[0], f1 = s[1];
    u16 o[8] = {f2bf(f0.x), f2bf(f0.y), f2bf(f0.z), f2bf(f0.w),
                f2bf(f1.x), f2bf(f1.y), f2bf(f1.z), f2bf(f1.w)};
    *(uint4*)(dst + (size_t)i * 8) = *(const uint4*)o;
  } else if (bid < 8192) {
    const int idx = bid - 6144;
    const float* w = (idx >= 1024) ? wk_w : wq_w;
    u16* out = (idx >= 1024) ? Wkr : Wqr;
    const int o = idx & 1023;
    for (int j = tid; j < 3072; j += 256) {
      int i = j / 3, t = j - i * 3;
      out[(size_t)o * 3072 + t * 1024 + i] = f2bf(w[(size_t)o * 3072 + j]);
    }
  } else {
    const int idx = bid - 8192;
    const float* w = (idx >= 1024) ? wc_w : wv_w;
    u16* out = (idx >= 1024) ? Wcr : Wvr;
    const int bx = idx & 1023;
    size_t i = (size_t)bx * 1024 + tid * 4;
    float4 f = *(const float4*)(w + i);
    u16 o4[4] = {f2bf(f.x), f2bf(f.y), f2bf(f.z), f2bf(f.w)};
    *(ushort4*)(out + i) = *(const ushort4*)o4;
  }
}

// ---------------------------------------------------------------------------
// Merged Q/K/V projection GEMM. grid (32, 8, 3). 128x128 tile, BK=32.
// 2-deep counted-vmcnt pipeline; NEW this round: MFMA cluster sits directly
// after the ds_reads (no lgkmcnt(0) wall) so the compiler emits fine-grained
// lgkmcnt(N) interleaving read latency with MFMA issue; the read-done
// barrier moves AFTER the MFMAs (register-only, semantically identical).
// sched_barrier(0) pins reads/MFMA above the staging region (rule #18).
// ---------------------------------------------------------------------------
__global__ __launch_bounds__(256) void mfma_proj(
    const u16* __restrict__ Xq, const u16* __restrict__ Xk,
    const u16* __restrict__ Xv, const u16* __restrict__ Wq,
    const u16* __restrict__ Wk, const u16* __restrict__ Wv,
    const float* __restrict__ bq, const float* __restrict__ bk,
    const float* __restrict__ bv, u16* __restrict__ Qhb,
    u16* __restrict__ Khb, u16* __restrict__ Vtb,
    const u16* __restrict__ zbuf) {
  __shared__ __attribute__((aligned(16))) u16 As2[2][128][40];
  __shared__ __attribute__((aligned(16))) u16 Bs2[2][128][40];
  const int z = blockIdx.z;
  const u16* __restrict__ Xb = (z == 0) ? Xq : (z == 1) ? Xk : Xv;
  const u16* __restrict__ Wr = (z == 0) ? Wq : (z == 1) ? Wk : Wv;
  const float* __restrict__ bias = (z == 0) ? bq : (z == 1) ? bk : bv;
  u16* __restrict__ Cptr = (z == 0) ? Qhb : (z == 1) ? Khb : Vtb;
  const int nk = (z == 2) ? 32 : 96;
  const bool conv = (z < 2);
  const bool vout = (z == 2);
  const float scale = (z == 0) ? 0.125f : 1.0f;
  const int Kdim = (z == 2) ? 1024 : 3072;

  const int tid = threadIdx.x;
  const int lane = tid & 63;
  const int w = tid >> 6;
  const int ln = tid & 15;
  const int quad = (tid >> 4) & 3;
  const int wrow = w >> 1, wcol = w & 1;
  const int m0 = blockIdx.x * 128, n0 = blockIdx.y * 128;

  // ---- hoisted per-slot staging state (slot i: c = w + 4i) ----
  const char* p[5];
  int dinc[5];
  u32 ldso[5];
  bool act[5], isA[5], loA[5], hiA[5];
  const char* pbaseA[5];

#pragma unroll
  for (int i = 0; i < 5; ++i) {
    int c = w + 4 * i;
    isA[i] = (c < 10);
    if (c < 10) {
      int G = c * 64 + lane;
      int x = G / 5, kb = G - x * 5;
      int gm = m0 + x;
      int b = gm >> 11, s = gm & 2047;
      act[i] = (kb < 4);
      ldso[i] = c * 1024;
      const char* pb = (const char*)(Xb + (size_t)(b * SS + s) * DDIM + kb * 8);
      pbaseA[i] = pb;
      loA[i] = (s == 0);
      hiA[i] = (s == 2047);
      if (conv) {
        p[i] = loA[i] ? (const char*)zbuf : (pb - 2048);  // t=0: row s-1
        dinc[i] = loA[i] ? 0 : 64;
      } else {
        p[i] = pb;
        dinc[i] = 64;
      }
    } else {
      int c2 = c - 10;
      int G = c2 * 64 + lane;
      int x = G / 5, kb = G - x * 5;
      act[i] = (kb < 4);
      ldso[i] = c2 * 1024;
      p[i] = (const char*)(Wr + (size_t)(n0 + x) * Kdim + kb * 8);
      dinc[i] = 64;
      pbaseA[i] = nullptr;
      loA[i] = hiA[i] = false;
    }
  }

  // each call issues EXACTLY 5 gld16 per wave (vmcnt accounting relies on it)
  auto stage = [&](int bi) {
#pragma unroll
    for (int i = 0; i < 5; ++i) {
      char* dst = (isA[i] ? (char*)As2[bi] : (char*)Bs2[bi]) + ldso[i];
      if (act[i]) gld16(p[i], dst);
      p[i] += dinc[i];
    }
  };

  f32x4_t acc[4][4];
#pragma unroll
  for (int i = 0; i < 4; ++i)
#pragma unroll
    for (int j = 0; j < 4; ++j) acc[i][j] = (f32x4_t){0.f, 0.f, 0.f, 0.f};

  stage(0);  // tile 0 -> buf 0
  stage(1);  // tile 1 -> buf 1 (10 outstanding/wave)

#pragma unroll 2
  for (int ks = 0; ks < nk; ++ks) {
    const int cur = ks & 1;
    // wait for tile-ks loads (oldest 5); keep tile ks+1 in flight
    if (ks + 1 < nk)
      asm volatile("s_waitcnt vmcnt(5)\ns_barrier" ::: "memory");
    else
      asm volatile("s_waitcnt vmcnt(0)\ns_barrier" ::: "memory");

    const u16(*As)[40] = As2[cur];
    const u16(*Bs)[40] = Bs2[cur];
    bf16x8_t a[4], b[4];
#pragma unroll
    for (int mt = 0; mt < 4; ++mt)
      a[mt] = *(const bf16x8_t*)&As[wrow * 64 + mt * 16 + ln][quad * 8];
#pragma unroll
    for (int nt = 0; nt < 4; ++nt)
      b[nt] = *(const bf16x8_t*)&Bs[wcol * 64 + nt * 16 + ln][quad * 8];
    // MFMAs directly after reads: compiler emits fine-grained lgkmcnt
    __builtin_amdgcn_s_setprio(1);
#pragma unroll
    for (int mt = 0; mt < 4; ++mt)
#pragma unroll
      for (int nt = 0; nt < 4; ++nt)
        acc[mt][nt] = __builtin_amdgcn_mfma_f32_16x16x32_bf16(
            a[mt], b[nt], acc[mt][nt], 0, 0, 0);
    __builtin_amdgcn_s_setprio(0);

    // all my reads done (MFMA consumed them); sync, then refill buf cur
    asm volatile("s_waitcnt lgkmcnt(0)\ns_barrier" ::: "memory");
    __builtin_amdgcn_sched_barrier(0);  // keep reads/MFMA above this point

    const int j = ks + 2;
    if (j < nk) {
      if (conv && (j & 31) == 0) {  // staged tile crosses a t-phase boundary
#pragma unroll
        for (int i = 0; i < 5; ++i) {
          if (isA[i]) {
            if (j == 32) {  // entering t=1: unfreeze s==0 rows
              if (loA[i]) { p[i] = pbaseA[i]; dinc[i] = 64; }
            } else {        // entering t=2: freeze s==2047 rows
              if (hiA[i]) { p[i] = (const char*)zbuf; dinc[i] = 0; }
            }
          }
        }
      }
      stage(cur);  // tile ks+2 -> just-freed buffer; flies over iter ks+1
    }
  }

#pragma unroll
  for (int mt = 0; mt < 4; ++mt) {
#pragma unroll
    for (int nt = 0; nt < 4; ++nt) {
      int gn = n0 + wcol * 64 + nt * 16 + ln;
      float bi = bias[gn];
#pragma unroll
      for (int r = 0; r < 4; ++r) {
        int gm = m0 + wrow * 64 + mt * 16 + quad * 4 + r;
        float val = (acc[mt][nt][r] + bi) * scale;
        int b = gm >> 11, s = gm & 2047;
        int hh = gn & 15, dd = gn >> 4;  // channel = dd*16 + hh (head FAST)
        if (!vout)
          Cptr[((size_t)(b * 16 + hh) * SS + s) * 64 + dd] = f2bf(val);
        else
          Cptr[((size_t)(b * 16 + hh) * 64 + dd) * SS + s] = f2bf(val);
      }
    }
  }
}

// ---------------------------------------------------------------------------
// Final linear GEMM. 32x128 tile, grid (128, 8). Same restructured loop.
// Per-wave issue counts: w0=4, w1..3=3.
// ---------------------------------------------------------------------------
__global__ __launch_bounds__(256) void mfma_gemm_lin(
    const u16* __restrict__ Xb, const u16* __restrict__ Wr,
    const float* __restrict__ bias, float* __restrict__ Cptr) {
  __shared__ __attribute__((aligned(16))) u16 As2[2][32][40];
  __shared__ __attribute__((aligned(16))) u16 Bs2[2][128][40];
  const int tid = threadIdx.x;
  const int lane = tid & 63;
  const int w = tid >> 6;
  const int ln = tid & 15;
  const int quad = (tid >> 4) & 3;
  const int wrow = w >> 1, wcol = w & 1;
  const int m0 = blockIdx.x * 32, n0 = blockIdx.y * 128;

  const char* p[4];
  u32 ldso[4];
  bool ok[4], act[4], isA[4];
#pragma unroll
  for (int i = 0; i < 4; ++i) {
    int c = w + 4 * i;
    ok[i] = (c < 13);
    if (c < 3) {
      int G = c * 64 + lane;
      int x = G / 5, kb = G - x * 5;
      isA[i] = true;
      act[i] = (kb < 4) && (x < 32);
      ldso[i] = c * 1024;
      p[i] = (const char*)(Xb + (size_t)(m0 + x) * DDIM + kb * 8);
    } else if (c < 13) {
      int c2 = c - 3;
      int G = c2 * 64 + lane;
      int x = G / 5, kb = G - x * 5;
      isA[i] = false;
      act[i] = (kb < 4);
      ldso[i] = c2 * 1024;
      p[i] = (const char*)(Wr + (size_t)(n0 + x) * 1024 + kb * 8);
    } else {
      isA[i] = false; act[i] = false; ldso[i] = 0; p[i] = nullptr;
    }
  }

  auto stage = [&](int bi) {
#pragma unroll
    for (int i = 0; i < 4; ++i) {
      if (ok[i]) {
        char* dst = (isA[i] ? (char*)As2[bi] : (char*)Bs2[bi]) + ldso[i];
        if (act[i]) gld16(p[i], dst);
        p[i] += 64;
      }
    }
  };

  f32x4_t acc[4];
#pragma unroll
  for (int j = 0; j < 4; ++j) acc[j] = (f32x4_t){0.f, 0.f, 0.f, 0.f};

  stage(0);
  stage(1);

#pragma unroll 2
  for (int ks = 0; ks < 32; ++ks) {
    const int cur = ks & 1;
    if (ks + 1 < 32) {
      if (w == 0) asm volatile("s_waitcnt vmcnt(4)\ns_barrier" ::: "memory");
      else        asm volatile("s_waitcnt vmcnt(3)\ns_barrier" ::: "memory");
    } else {
      asm volatile("s_waitcnt vmcnt(0)\ns_barrier" ::: "memory");
    }

    const u16(*As)[40] = As2[cur];
    const u16(*Bs)[40] = Bs2[cur];
    bf16x8_t a = *(const bf16x8_t*)&As[wrow * 16 + ln][quad * 8];
    bf16x8_t b[4];
#pragma unroll
    for (int nt = 0; nt < 4; ++nt)
      b[nt] = *(const bf16x8_t*)&Bs[wcol * 64 + nt * 16 + ln][quad * 8];
    __builtin_amdgcn_s_setprio(1);
#pragma unroll
    for (int nt = 0; nt < 4; ++nt)
      acc[nt] = __builtin_amdgcn_mfma_f32_16x16x32_bf16(a, b[nt], acc[nt], 0, 0, 0);
    __builtin_amdgcn_s_setprio(0);

    asm volatile("s_waitcnt lgkmcnt(0)\ns_barrier" ::: "memory");
    __builtin_amdgcn_sched_barrier(0);

    if (ks + 2 < 32) stage(cur);
  }

#pragma unroll
  for (int nt = 0; nt < 4; ++nt) {
    int gn = n0 + wcol * 64 + nt * 16 + ln;
    float bi = bias[gn];
#pragma unroll
    for (int r = 0; r < 4; ++r) {
      int gm = m0 + wrow * 16 + quad * 4 + r;
      Cptr[(size_t)gm * DDIM + gn] = acc[nt][r] + bi;
    }
  }
}

// ---------------------------------------------------------------------------
// MFMA flash attention. NEW: wave-shared running max (exact: shared max >=
// row max so P<=1; scale cancels in P*V/sum(P); bf16 relative precision is
// magnitude-independent). 6 shfl + 1 rescale-exp per tile vs 16 + 4.
// 2-deep counted pipeline retained; sched_barrier(0) before bottom stage.
// ---------------------------------------------------------------------------
__global__ __launch_bounds__(256) void mfma_attn(
    const u16* __restrict__ Qhb, const u16* __restrict__ Khb,
    const u16* __restrict__ Vtb, u16* __restrict__ Aob,
    const u16* __restrict__ zbuf) {
  __shared__ __attribute__((aligned(16))) u16 Ks2[2][64][72];
  __shared__ __attribute__((aligned(16))) u16 Vt2[2][64][72];
  __shared__ __attribute__((aligned(16))) u16 Ps[4][16][72];
  const int tid = threadIdx.x;
  const int lane = tid & 63;
  const int w = tid >> 6;
  const int ln = tid & 15;
  const int quad = (tid >> 4) & 3;
  const int bh = blockIdx.y;
  const int b = bh >> 4, hh = bh & 15;
  const int s0 = blockIdx.x * 64;

  const char* p[5];
  int dinc[5];
  u32 ldso[5];
  bool ok[5], act[5], isK[5];
#pragma unroll
  for (int i = 0; i < 5; ++i) {
    int c = w + 4 * i;
    ok[i] = (c < 18);
    if (c < 9) {
      int G = c * 64 + lane;
      int x = G / 9, db = G - x * 9;
      isK[i] = true;
      act[i] = (db < 8);
      ldso[i] = c * 1024;
      p[i] = (const char*)(Khb + ((size_t)bh * SS + x) * 64 + db * 8);
      dinc[i] = 8192;
    } else if (c < 18) {
      int c2 = c - 9;
      int G = c2 * 64 + lane;
      int x = G / 9, db = G - x * 9;
      isK[i] = false;
      act[i] = (db < 8);
      ldso[i] = c2 * 1024;
      p[i] = (const char*)(Vtb + ((size_t)bh * 64 + x) * SS + db * 8);
      dinc[i] = 128;
    } else {
      isK[i] = false; ok[i] = false; act[i] = false; ldso[i] = 0;
      p[i] = nullptr; dinc[i] = 0;
    }
  }

  auto stage = [&](int bi) {
#pragma unroll
    for (int i = 0; i < 5; ++i) {
      if (ok[i]) {
        char* dst = (isK[i] ? (char*)Ks2[bi] : (char*)Vt2[bi]) + ldso[i];
        if (act[i]) gld16(p[i], dst);
        p[i] += dinc[i];
      }
    }
  };

  const u16* qp = Qhb + ((size_t)bh * SS + s0 + w * 16 + ln) * 64 + quad * 8;
  bf16x8_t qf0 = *(const bf16x8_t*)qp;
  bf16x8_t qf1 = *(const bf16x8_t*)(qp + 32);

  float mrow = -3e38f;  // wave-shared running max
  float lsum[4];
  f32x4_t oacc[4];
#pragma unroll
  for (int r = 0; r < 4; ++r) lsum[r] = 0.f;
#pragma unroll
  for (int dt = 0; dt < 4; ++dt) oacc[dt] = (f32x4_t){0.f, 0.f, 0.f, 0.f};

  stage(0);
  stage(1);

#pragma unroll 2
  for (int kt = 0; kt < 32; ++kt) {
    const int cur = kt & 1;
    if (kt + 1 < 32) {
      if (w < 2) asm volatile("s_waitcnt vmcnt(5)\ns_barrier" ::: "memory");
      else       asm volatile("s_waitcnt vmcnt(4)\ns_barrier" ::: "memory");
    } else {
      asm volatile("s_waitcnt vmcnt(0)\ns_barrier" ::: "memory");
    }

    const u16(*Ks)[72] = Ks2[cur];
    const u16(*Vt)[72] = Vt2[cur];

    f32x4_t sc[4];
#pragma unroll
    for (int nt = 0; nt < 4; ++nt) sc[nt] = (f32x4_t){0.f, 0.f, 0.f, 0.f};
    __builtin_amdgcn_s_setprio(1);
#pragma unroll
    for (int nt = 0; nt < 4; ++nt) {
      bf16x8_t k0f = *(const bf16x8_t*)&Ks[nt * 16 + ln][quad * 8];
      sc[nt] = __builtin_amdgcn_mfma_f32_16x16x32_bf16(qf0, k0f, sc[nt], 0, 0, 0);
      bf16x8_t k1f = *(const bf16x8_t*)&Ks[nt * 16 + ln][32 + quad * 8];
      sc[nt] = __builtin_amdgcn_mfma_f32_16x16x32_bf16(qf1, k1f, sc[nt], 0, 0, 0);
    }
    __builtin_amdgcn_s_setprio(0);

    // wave-shared max: local max over 16 regs, then 6-shfl full-wave reduce
    float mx = sc[0][0];
#pragma unroll
    for (int nt = 0; nt < 4; ++nt)
#pragma unroll
      for (int r = 0; r < 4; ++r) mx = fmaxf(mx, sc[nt][r]);
    mx = fmaxf(mx, __shfl_xor(mx, 1, 64));
    mx = fmaxf(mx, __shfl_xor(mx, 2, 64));
    mx = fmaxf(mx, __shfl_xor(mx, 4, 64));
    mx = fmaxf(mx, __shfl_xor(mx, 8, 64));
    mx = fmaxf(mx, __shfl_xor(mx, 16, 64));
    mx = fmaxf(mx, __shfl_xor(mx, 32, 64));
    if (mx > mrow) {  // wave-uniform branch
      float al = __expf(mrow - mx);
      mrow = mx;
#pragma unroll
      for (int r = 0; r < 4; ++r) lsum[r] *= al;
#pragma unroll
      for (int dt = 0; dt < 4; ++dt)
#pragma unroll
        for (int r = 0; r < 4; ++r) oacc[dt][r] *= al;
    }
#pragma unroll
    for (int r = 0; r < 4; ++r) {
      float p0 = __expf(sc[0][r] - mrow), p1 = __expf(sc[1][r] - mrow);
      float p2 = __expf(sc[2][r] - mrow), p3 = __expf(sc[3][r] - mrow);
      lsum[r] += p0 + p1 + p2 + p3;
      Ps[w][quad * 4 + r][ln] = f2bf(p0);
      Ps[w][quad * 4 + r][16 + ln] = f2bf(p1);
      Ps[w][quad * 4 + r][32 + ln] = f2bf(p2);
      Ps[w][quad * 4 + r][48 + ln] = f2bf(p3);
    }

    // PV (P read back in A-operand layout; same-wave LDS program order)
    bf16x8_t pa0 = *(const bf16x8_t*)&Ps[w][ln][quad * 8];
    bf16x8_t pa1 = *(const bf16x8_t*)&Ps[w][ln][32 + quad * 8];
    __builtin_amdgcn_s_setprio(1);
#pragma unroll
    for (int dt = 0; dt < 4; ++dt) {
      bf16x8_t v0f = *(const bf16x8_t*)&Vt[dt * 16 + ln][quad * 8];
      oacc[dt] = __builtin_amdgcn_mfma_f32_16x16x32_bf16(pa0, v0f, oacc[dt], 0, 0, 0);
      bf16x8_t v1f = *(const bf16x8_t*)&Vt[dt * 16 + ln][32 + quad * 8];
      oacc[dt] = __builtin_amdgcn_mfma_f32_16x16x32_bf16(pa1, v1f, oacc[dt], 0, 0, 0);
    }
    __builtin_amdgcn_s_setprio(0);

    asm volatile("s_waitcnt lgkmcnt(0)\ns_barrier" ::: "memory");
    __builtin_amdgcn_sched_barrier(0);
    if (kt + 2 < 32) stage(cur);  // tile kt+2; flies over all of iter kt+1
  }

  // epilogue: reduce lane-partial sums once, normalize, store
  float inv[4];
#pragma unroll
  for (int r = 0; r < 4; ++r) {
    float t = lsum[r];
    t += __shfl_xor(t, 1, 64);
    t += __shfl_xor(t, 2, 64);
    t += __shfl_xor(t, 4, 64);
    t += __shfl_xor(t, 8, 64);
    inv[r] = 1.f / t;
  }
#pragma unroll
  for (int dt = 0; dt < 4; ++dt)
#pragma unroll
    for (int r = 0; r < 4; ++r) {
      int gm = b * SS + s0 + w * 16 + quad * 4 + r;
      Aob[(size_t)gm * DDIM + hh * 64 + dt * 16 + ln] = f2bf(oacc[dt][r] * inv[r]);
    }
}

// ---------------------------------------------------------------------------
// Launch
// ---------------------------------------------------------------------------
extern "C" void kernel_launch(void* const* d_in, const int* in_sizes, int n_in,
                              void* d_out, int out_size, void* d_ws, size_t ws_size,
                              hipStream_t stream) {
  const float* q    = (const float*)d_in[0];
  const float* k    = (const float*)d_in[1];
  const float* v    = (const float*)d_in[2];
  const float* wq_w = (const float*)d_in[3];
  const float* wq_b = (const float*)d_in[4];
  const float* wk_w = (const float*)d_in[5];
  const float* wk_b = (const float*)d_in[6];
  const float* wv_w = (const float*)d_in[7];
  const float* wv_b = (const float*)d_in[8];
  const float* wc_w = (const float*)d_in[9];
  const float* wc_b = (const float*)d_in[10];

  char* ws = (char*)d_ws;
  size_t off = 0;
  u16* zbuf = (u16*)(ws + off); off += 256;
  const size_t SZ_ACT = (size_t)2 * SS * DDIM * 2;  // 8 MB bf16
  u16* Xq  = (u16*)(ws + off); off += SZ_ACT;
  u16* Xk  = (u16*)(ws + off); off += SZ_ACT;
  u16* Xv  = (u16*)(ws + off); off += SZ_ACT;
  u16* Wqr = (u16*)(ws + off); off += (size_t)1024 * 3072 * 2;
  u16* Wkr = (u16*)(ws + off); off += (size_t)1024 * 3072 * 2;
  u16* Wvr = (u16*)(ws + off); off += (size_t)1024 * 1024 * 2;
  u16* Wcr = (u16*)(ws + off); off += (size_t)1024 * 1024 * 2;
  u16* Qhb = (u16*)(ws + off); off += SZ_ACT;
  u16* Khb = (u16*)(ws + off); off += SZ_ACT;
  u16* Vtb = (u16*)(ws + off); off += SZ_ACT;
  u16* Aob = (u16*)(ws + off); off += SZ_ACT;
  if (ws_size < off) return;

  prep_kernel<<<10240, 256, 0, stream>>>(q, k, v, wq_w, wk_w, wv_w, wc_w,
                                         Xq, Xk, Xv, Wqr, Wkr, Wvr, Wcr,
                                         (u32*)zbuf);

  // merged Q/K/V projections: 2-deep counted-vmcnt pipeline
  mfma_proj<<<dim3(32, 8, 3), 256, 0, stream>>>(
      Xq, Xk, Xv, Wqr, Wkr, Wvr, wq_b, wk_b, wv_b, Qhb, Khb, Vtb, zbuf);

  mfma_attn<<<dim3(32, 32), 256, 0, stream>>>(Qhb, Khb, Vtb, Aob, zbuf);

  mfma_gemm_lin<<<dim3(128, 8), 256, 0, stream>>>(Aob, Wcr, wc_b, (float*)d_out);
}